// Round 7
// baseline (1024.755 us; speedup 1.0000x reference)
//
#include <hip/hip_runtime.h>
#include <hip/hip_bf16.h>

#define NN 50000
#define NNP 50016   // padded to 32*1563
#define NE 800000
#define NG 256

typedef __attribute__((ext_vector_type(8))) short short8;
typedef __attribute__((ext_vector_type(8))) unsigned short ushort8;
typedef __attribute__((ext_vector_type(4))) float f32x4;

struct __align__(8) Edge { int s; float c; };

__device__ __forceinline__ float u2f(unsigned short u) {
  unsigned int t = ((unsigned int)u) << 16;
  return __builtin_bit_cast(float, t);
}
__device__ __forceinline__ unsigned short f2b(float f) {
  __hip_bfloat16 b = __float2bfloat16(f);
  return __builtin_bit_cast(unsigned short, b);
}
__device__ __forceinline__ f32x4 mfma_bf16(short8 a, short8 b, f32x4 c) {
  return __builtin_amdgcn_mfma_f32_16x16x32_bf16(a, b, c, 0, 0, 0);
}
__device__ __forceinline__ void fma8(float* acc, float c, const ushort8& v) {
  #pragma unroll
  for (int j = 0; j < 8; j++) acc[j] += c * u2f(v[j]);
}

// ring-slot macros: guarded refill (en<e1) + guarded consume (eoff<cnt).
// consume order per node == plain edge order -> bitwise-identical sums.
#define GRAMP(vv, cc, S, E0, CNT, BASE, STRIDE)                         \
  if ((S) < (CNT)) { Edge ed = ecs[(E0) + (S)]; cc = ed.c;              \
    vv = *(const ushort8*)((BASE) + (size_t)ed.s * (STRIDE) + cb); }    \
  else { cc = 0.f; vv = (ushort8)0; }

#define GSTEP(vv, cc, acc, EOFF, E0, E1, CNT, BASE, STRIDE)             \
  { ushort8 tv = vv; float tc = cc; int en = (E0) + (EOFF) + 4;         \
    if (en < (E1)) { Edge ed = ecs[en]; cc = ed.c;                      \
      vv = *(const ushort8*)((BASE) + (size_t)ed.s * (STRIDE) + cb); }  \
    if ((EOFF) < (CNT)) fma8(acc, tc, tv); }

// ---------------- CSR build ----------------
__global__ void k_zero_i32(int* __restrict__ p, int n) {
  int i = blockIdx.x * blockDim.x + threadIdx.x;
  if (i < n) p[i] = 0;
}
__global__ void k_zero_f32(float* __restrict__ p, int n) {
  int i = blockIdx.x * blockDim.x + threadIdx.x;
  if (i < n) p[i] = 0.f;
}
__global__ void k_count(const int* __restrict__ dst, int* __restrict__ counts, int E) {
  int e = blockIdx.x * blockDim.x + threadIdx.x;
  if (e < E) atomicAdd(&counts[dst[e]], 1);
}
__global__ void k_dinv(const int* __restrict__ counts, float* __restrict__ dinv,
                       float* __restrict__ selfc, int n) {
  int i = blockIdx.x * blockDim.x + threadIdx.x;
  if (i < n) {
    float d = (float)counts[i] + 1.0f;
    dinv[i]  = rsqrtf(d);
    selfc[i] = 1.0f / d;
  }
}
__global__ void k_scan(const int* __restrict__ counts, int* __restrict__ row_ptr,
                       int* __restrict__ fill, int n) {
  __shared__ int wsum[16];
  __shared__ int carry_s;
  int tid = threadIdx.x;
  if (tid == 0) carry_s = 0;
  __syncthreads();
  for (int base = 0; base < n; base += 1024) {
    int i = base + tid;
    int v = (i < n) ? counts[i] : 0;
    int incl = v;
    #pragma unroll
    for (int off = 1; off < 64; off <<= 1) {
      int t = __shfl_up(incl, off, 64);
      if ((tid & 63) >= off) incl += t;
    }
    int wid = tid >> 6;
    if ((tid & 63) == 63) wsum[wid] = incl;
    __syncthreads();
    if (tid < 16) {
      int s = wsum[tid];
      #pragma unroll
      for (int off = 1; off < 16; off <<= 1) {
        int t = __shfl_up(s, off, 16);
        if (tid >= off) s += t;
      }
      wsum[tid] = s;
    }
    __syncthreads();
    int waveoff = (wid == 0) ? 0 : wsum[wid - 1];
    int carry = carry_s;
    int excl = carry + waveoff + incl - v;
    if (i < n) { row_ptr[i] = excl; fill[i] = 0; }
    if (i == n - 1) row_ptr[n] = excl + v;
    __syncthreads();
    if (tid == 0) carry_s = carry + wsum[15];
    __syncthreads();
  }
}
__global__ void k_fill(const int* __restrict__ src, const int* __restrict__ dst,
                       const int* __restrict__ row_ptr, int* __restrict__ fill,
                       const float* __restrict__ dinv, Edge* __restrict__ ecs, int E) {
  int e = blockIdx.x * blockDim.x + threadIdx.x;
  if (e < E) {
    int s = src[e], d = dst[e];
    int pos = row_ptr[d] + atomicAdd(&fill[d], 1);
    Edge ed; ed.s = s; ed.c = dinv[s] * dinv[d];
    ecs[pos] = ed;
  }
}

// ---------------- weight prep: bf16 transposed [N][K] with zero pad ----------------
__global__ void k_prep_w1t(const float* __restrict__ W1, unsigned short* __restrict__ W1t) {
  int idx = blockIdx.x * blockDim.x + threadIdx.x;   // 512*32
  if (idx < 512 * 32) {
    int n = idx >> 5, k = idx & 31;
    float v = (n < 500 && k < 19) ? W1[k * 500 + n] : 0.f;
    W1t[idx] = f2b(v);
  }
}
__global__ void k_prep_w2t(const float* __restrict__ W2, unsigned short* __restrict__ W2t) {
  int idx = blockIdx.x * blockDim.x + threadIdx.x;   // 416*512
  if (idx < 416 * 512) {
    int n = idx >> 9, k = idx & 511;
    float v = (n < 400 && k < 500) ? W2[k * 400 + n] : 0.f;
    W2t[idx] = f2b(v);
  }
}
__global__ void k_prep_w3t(const float* __restrict__ W3, unsigned short* __restrict__ W3t) {
  int idx = blockIdx.x * blockDim.x + threadIdx.x;   // 320*416
  if (idx < 320 * 416) {
    int n = idx / 416, k = idx - n * 416;
    float v = (n < 300 && k < 400) ? W3[k * 300 + n] : 0.f;
    W3t[idx] = f2b(v);
  }
}
__global__ void k_prep_b1(const float* __restrict__ b1, float* __restrict__ b1p) {
  int i = blockIdx.x * blockDim.x + threadIdx.x;
  if (i < 512) b1p[i] = (i < 500) ? b1[i] : 0.f;
}

// ---------------- layer-1 aggregation of x -> bf16 [NNP][32] ----------------
__global__ __launch_bounds__(256) void k_agg_x(
    const float* __restrict__ x, const int* __restrict__ row_ptr,
    const Edge* __restrict__ ecs, const float* __restrict__ selfc,
    unsigned short* __restrict__ aggxb, int n) {
  int tid  = threadIdx.x;
  int node = blockIdx.x * 8 + (tid >> 5);
  int lane = tid & 31;
  if (node >= NNP) return;
  float acc = 0.f;
  if (node < n && lane < 19) {
    int e0 = row_ptr[node], e1 = row_ptr[node + 1];
    int cnt = e1 - e0;
    float v0 = 0.f, v1 = 0.f, v2 = 0.f, v3 = 0.f;
    float c0 = 0.f, c1 = 0.f, c2 = 0.f, c3 = 0.f;
    if (cnt > 0) { Edge ed = ecs[e0];     c0 = ed.c; v0 = x[(size_t)ed.s * 19 + lane]; }
    if (cnt > 1) { Edge ed = ecs[e0 + 1]; c1 = ed.c; v1 = x[(size_t)ed.s * 19 + lane]; }
    if (cnt > 2) { Edge ed = ecs[e0 + 2]; c2 = ed.c; v2 = x[(size_t)ed.s * 19 + lane]; }
    if (cnt > 3) { Edge ed = ecs[e0 + 3]; c3 = ed.c; v3 = x[(size_t)ed.s * 19 + lane]; }
    for (int e = 0; e < cnt; e += 4) {
      float tv, tc; int en;
      tv = v0; tc = c0; en = e0 + e + 4;
      if (en < e1) { Edge ed = ecs[en]; c0 = ed.c; v0 = x[(size_t)ed.s * 19 + lane]; }
      if (e < cnt) acc += tc * tv;
      tv = v1; tc = c1; en = e0 + e + 5;
      if (en < e1) { Edge ed = ecs[en]; c1 = ed.c; v1 = x[(size_t)ed.s * 19 + lane]; }
      if (e + 1 < cnt) acc += tc * tv;
      tv = v2; tc = c2; en = e0 + e + 6;
      if (en < e1) { Edge ed = ecs[en]; c2 = ed.c; v2 = x[(size_t)ed.s * 19 + lane]; }
      if (e + 2 < cnt) acc += tc * tv;
      tv = v3; tc = c3; en = e0 + e + 7;
      if (en < e1) { Edge ed = ecs[en]; c3 = ed.c; v3 = x[(size_t)ed.s * 19 + lane]; }
      if (e + 3 < cnt) acc += tc * tv;
    }
    acc += selfc[node] * x[(size_t)node * 19 + lane];
  }
  aggxb[(size_t)node * 32 + lane] = (node < n && lane < 19) ? f2b(acc) : (unsigned short)0;
}

// ---- fused layer1+2: T2 = (relu(aggx@W1+b1)) @ W2, MFMA, H1 tile in LDS ----
__global__ __launch_bounds__(256) void k_fused12(
    const unsigned short* __restrict__ aggxb, const unsigned short* __restrict__ W1t,
    const float* __restrict__ b1p, const unsigned short* __restrict__ W2t,
    unsigned short* __restrict__ T2) {
  __shared__ unsigned short Hs[32][520];
  int tid = threadIdx.x;
  int lane = tid & 63, wv = tid >> 6;
  int l15 = lane & 15, quad = lane >> 4;
  int r0 = blockIdx.x * 32;
  for (int t = wv; t < 64; t += 4) {
    int rt = t & 1, ct = t >> 1;
    short8 a = *(const short8*)(aggxb + (size_t)(r0 + rt * 16 + l15) * 32 + quad * 8);
    short8 b = *(const short8*)(W1t + (size_t)(ct * 16 + l15) * 32 + quad * 8);
    f32x4 c = {0.f, 0.f, 0.f, 0.f};
    c = mfma_bf16(a, b, c);
    int col = ct * 16 + l15;
    float bias = b1p[col];
    int rbase = rt * 16 + quad * 4;
    #pragma unroll
    for (int r = 0; r < 4; r++)
      Hs[rbase + r][col] = f2b(fmaxf(c[r] + bias, 0.f));
  }
  __syncthreads();
  int rt = wv >> 1, p = wv & 1;
  f32x4 acc[13];
  #pragma unroll
  for (int j = 0; j < 13; j++) acc[j] = (f32x4){0.f, 0.f, 0.f, 0.f};
  for (int k0 = 0; k0 < 512; k0 += 32) {
    short8 a = *(const short8*)&Hs[rt * 16 + l15][k0 + quad * 8];
    #pragma unroll
    for (int j = 0; j < 13; j++) {
      int n = (p + 2 * j) * 16 + l15;
      short8 b = *(const short8*)(W2t + (size_t)n * 512 + k0 + quad * 8);
      acc[j] = mfma_bf16(a, b, acc[j]);
    }
  }
  int rr = r0 + rt * 16 + quad * 4;
  #pragma unroll
  for (int j = 0; j < 13; j++) {
    int n = (p + 2 * j) * 16 + l15;
    if (n < 400) {
      #pragma unroll
      for (int r = 0; r < 4; r++) {
        int row = rr + r;
        if (row < NN) T2[(size_t)row * 400 + n] = f2b(acc[j][r]);
      }
    }
  }
}

// ---- fused layer2 agg + layer3 linear: T3 = relu(agg(T2)+b2) @ W3 (MFMA) ----
// phase A: TWO interleaved depth-4 rings per wave (8 outstanding row loads),
// guarded consume handles ragged degrees; order per node unchanged.
__global__ __launch_bounds__(256) void k_fused23(
    const unsigned short* __restrict__ T2, const int* __restrict__ row_ptr,
    const Edge* __restrict__ ecs, const float* __restrict__ selfc,
    const float* __restrict__ b2, const unsigned short* __restrict__ W3t,
    unsigned short* __restrict__ T3) {
  __shared__ unsigned short Hs[32][424];
  int tid = threadIdx.x;
  int lane = tid & 63, wv = tid >> 6;
  int l15 = lane & 15, quad = lane >> 4;
  int r0 = blockIdx.x * 32;
  bool act = lane < 50;
  int cb = lane * 8;
  for (int i = 0; i < 4; i++) {
    int nlA = wv + 8 * i, nlB = nlA + 4;
    int nodeA = r0 + nlA, nodeB = r0 + nlB;
    bool okA = nodeA < NN, okB = nodeB < NN;
    ushort8 outA = (ushort8)0, outB = (ushort8)0;
    if (act) {
      int e0A = 0, e1A = 0, e0B = 0, e1B = 0;
      if (okA) { e0A = row_ptr[nodeA]; e1A = row_ptr[nodeA + 1]; }
      if (okB) { e0B = row_ptr[nodeB]; e1B = row_ptr[nodeB + 1]; }
      int cntA = e1A - e0A, cntB = e1B - e0B;
      float accA[8], accB[8];
      #pragma unroll
      for (int j = 0; j < 8; j++) { accA[j] = 0.f; accB[j] = 0.f; }
      ushort8 vA0, vA1, vA2, vA3, vB0, vB1, vB2, vB3;
      float cA0, cA1, cA2, cA3, cB0, cB1, cB2, cB3;
      GRAMP(vA0, cA0, 0, e0A, cntA, T2, 400)
      GRAMP(vB0, cB0, 0, e0B, cntB, T2, 400)
      GRAMP(vA1, cA1, 1, e0A, cntA, T2, 400)
      GRAMP(vB1, cB1, 1, e0B, cntB, T2, 400)
      GRAMP(vA2, cA2, 2, e0A, cntA, T2, 400)
      GRAMP(vB2, cB2, 2, e0B, cntB, T2, 400)
      GRAMP(vA3, cA3, 3, e0A, cntA, T2, 400)
      GRAMP(vB3, cB3, 3, e0B, cntB, T2, 400)
      int mx = cntA > cntB ? cntA : cntB;
      for (int e = 0; e < mx; e += 4) {
        GSTEP(vA0, cA0, accA, e + 0, e0A, e1A, cntA, T2, 400)
        GSTEP(vB0, cB0, accB, e + 0, e0B, e1B, cntB, T2, 400)
        GSTEP(vA1, cA1, accA, e + 1, e0A, e1A, cntA, T2, 400)
        GSTEP(vB1, cB1, accB, e + 1, e0B, e1B, cntB, T2, 400)
        GSTEP(vA2, cA2, accA, e + 2, e0A, e1A, cntA, T2, 400)
        GSTEP(vB2, cB2, accB, e + 2, e0B, e1B, cntB, T2, 400)
        GSTEP(vA3, cA3, accA, e + 3, e0A, e1A, cntA, T2, 400)
        GSTEP(vB3, cB3, accB, e + 3, e0B, e1B, cntB, T2, 400)
      }
      if (okA) {
        ushort8 sv = *(const ushort8*)(T2 + (size_t)nodeA * 400 + cb);
        float sc = selfc[nodeA];
        #pragma unroll
        for (int j = 0; j < 8; j++)
          outA[j] = f2b(fmaxf(accA[j] + sc * u2f(sv[j]) + b2[cb + j], 0.f));
      }
      if (okB) {
        ushort8 sv = *(const ushort8*)(T2 + (size_t)nodeB * 400 + cb);
        float sc = selfc[nodeB];
        #pragma unroll
        for (int j = 0; j < 8; j++)
          outB[j] = f2b(fmaxf(accB[j] + sc * u2f(sv[j]) + b2[cb + j], 0.f));
      }
    }
    if (lane < 52) {
      *(ushort8*)&Hs[nlA][cb] = outA;
      *(ushort8*)&Hs[nlB][cb] = outB;
    }
  }
  __syncthreads();
  int rt = wv >> 1, p = wv & 1;
  f32x4 acc[10];
  #pragma unroll
  for (int j = 0; j < 10; j++) acc[j] = (f32x4){0.f, 0.f, 0.f, 0.f};
  for (int k0 = 0; k0 < 416; k0 += 32) {
    short8 a = *(const short8*)&Hs[rt * 16 + l15][k0 + quad * 8];
    #pragma unroll
    for (int j = 0; j < 10; j++) {
      int n = (p + 2 * j) * 16 + l15;
      short8 b = *(const short8*)(W3t + (size_t)n * 416 + k0 + quad * 8);
      acc[j] = mfma_bf16(a, b, acc[j]);
    }
  }
  int rr = r0 + rt * 16 + quad * 4;
  #pragma unroll
  for (int j = 0; j < 10; j++) {
    int n = (p + 2 * j) * 16 + l15;
    if (n < 300) {
      #pragma unroll
      for (int r = 0; r < 4; r++) {
        int row = rr + r;
        if (row < NN) T3[(size_t)row * 304 + n] = f2b(acc[j][r]);
      }
    }
  }
}

// ---- fused layer3 agg + bias + relu + per-graph max pool ----
// batch SORTED -> 4-slot LDS max table; two interleaved depth-4 rings per wave.
__global__ __launch_bounds__(256) void k_fused3m(
    const unsigned short* __restrict__ T3, const int* __restrict__ row_ptr,
    const Edge* __restrict__ ecs, const float* __restrict__ selfc,
    const float* __restrict__ b3, const int* __restrict__ batch,
    float* __restrict__ gbuf) {
  __shared__ unsigned int lmax[4][304];
  int tid = threadIdx.x;
  int lane = tid & 63, wv = tid >> 6;
  int r0 = blockIdx.x * 32;
  int g0 = batch[r0];
  for (int i = tid; i < 4 * 304; i += 256) ((unsigned int*)lmax)[i] = 0u;
  __syncthreads();
  bool act = lane < 38;
  int cb = lane * 8;
  for (int i = 0; i < 4; i++) {
    int nodeA = r0 + wv + 8 * i, nodeB = nodeA + 4;
    bool okA = nodeA < NN, okB = nodeB < NN;
    if (act) {
      int e0A = 0, e1A = 0, e0B = 0, e1B = 0;
      if (okA) { e0A = row_ptr[nodeA]; e1A = row_ptr[nodeA + 1]; }
      if (okB) { e0B = row_ptr[nodeB]; e1B = row_ptr[nodeB + 1]; }
      int cntA = e1A - e0A, cntB = e1B - e0B;
      float accA[8], accB[8];
      #pragma unroll
      for (int j = 0; j < 8; j++) { accA[j] = 0.f; accB[j] = 0.f; }
      ushort8 vA0, vA1, vA2, vA3, vB0, vB1, vB2, vB3;
      float cA0, cA1, cA2, cA3, cB0, cB1, cB2, cB3;
      GRAMP(vA0, cA0, 0, e0A, cntA, T3, 304)
      GRAMP(vB0, cB0, 0, e0B, cntB, T3, 304)
      GRAMP(vA1, cA1, 1, e0A, cntA, T3, 304)
      GRAMP(vB1, cB1, 1, e0B, cntB, T3, 304)
      GRAMP(vA2, cA2, 2, e0A, cntA, T3, 304)
      GRAMP(vB2, cB2, 2, e0B, cntB, T3, 304)
      GRAMP(vA3, cA3, 3, e0A, cntA, T3, 304)
      GRAMP(vB3, cB3, 3, e0B, cntB, T3, 304)
      int mx = cntA > cntB ? cntA : cntB;
      for (int e = 0; e < mx; e += 4) {
        GSTEP(vA0, cA0, accA, e + 0, e0A, e1A, cntA, T3, 304)
        GSTEP(vB0, cB0, accB, e + 0, e0B, e1B, cntB, T3, 304)
        GSTEP(vA1, cA1, accA, e + 1, e0A, e1A, cntA, T3, 304)
        GSTEP(vB1, cB1, accB, e + 1, e0B, e1B, cntB, T3, 304)
        GSTEP(vA2, cA2, accA, e + 2, e0A, e1A, cntA, T3, 304)
        GSTEP(vB2, cB2, accB, e + 2, e0B, e1B, cntB, T3, 304)
        GSTEP(vA3, cA3, accA, e + 3, e0A, e1A, cntA, T3, 304)
        GSTEP(vB3, cB3, accB, e + 3, e0B, e1B, cntB, T3, 304)
      }
      if (okA) {
        ushort8 sv = *(const ushort8*)(T3 + (size_t)nodeA * 304 + cb);
        float sc = selfc[nodeA];
        int slot = batch[nodeA] - g0;
        #pragma unroll
        for (int j = 0; j < 8; j++) {
          int c = cb + j;
          if (c < 300) {
            float v = fmaxf(accA[j] + sc * u2f(sv[j]) + b3[c], 0.f);
            unsigned int uv = __float_as_uint(v);
            if (slot < 4) atomicMax(&lmax[slot][c], uv);
            else atomicMax((unsigned int*)&gbuf[(size_t)(g0 + slot) * 300 + c], uv);
          }
        }
      }
      if (okB) {
        ushort8 sv = *(const ushort8*)(T3 + (size_t)nodeB * 304 + cb);
        float sc = selfc[nodeB];
        int slot = batch[nodeB] - g0;
        #pragma unroll
        for (int j = 0; j < 8; j++) {
          int c = cb + j;
          if (c < 300) {
            float v = fmaxf(accB[j] + sc * u2f(sv[j]) + b3[c], 0.f);
            unsigned int uv = __float_as_uint(v);
            if (slot < 4) atomicMax(&lmax[slot][c], uv);
            else atomicMax((unsigned int*)&gbuf[(size_t)(g0 + slot) * 300 + c], uv);
          }
        }
      }
    }
  }
  __syncthreads();
  for (int i = tid; i < 4 * 304; i += 256) {
    int s = i / 304, c = i - s * 304;
    unsigned int uv = lmax[s][c];
    int g = g0 + s;
    if (c < 300 && uv != 0u && g < NG)
      atomicMax((unsigned int*)&gbuf[(size_t)g * 300 + c], uv);
  }
}

// ---------------- small dense head ----------------
__global__ void k_linear(const float* __restrict__ A, const float* __restrict__ W,
                         const float* __restrict__ b, float* __restrict__ C,
                         int M, int N, int K, int relu) {
  int idx = blockIdx.x * blockDim.x + threadIdx.x;
  if (idx >= M * N) return;
  int m = idx / N, n = idx - m * N;
  float acc = b[n];
  for (int k = 0; k < K; k++) acc += A[m * K + k] * W[k * N + n];
  if (relu) acc = fmaxf(acc, 0.f);
  C[idx] = acc;
}

__global__ void k_softmax0(const float* __restrict__ logits, float* __restrict__ out) {
  __shared__ float cmax[6], csum[6];
  int g = threadIdx.x;
  if (g < 6) {
    float m = -1e30f;
    for (int i = 0; i < NG; i++) m = fmaxf(m, logits[i * 6 + g]);
    float s = 0.f;
    for (int i = 0; i < NG; i++) s += expf(logits[i * 6 + g] - m);
    cmax[g] = m; csum[g] = s;
  }
  __syncthreads();
  for (int c = 0; c < 6; c++)
    out[g * 6 + c] = expf(logits[g * 6 + c] - cmax[c]) / csum[c];
}

extern "C" void kernel_launch(void* const* d_in, const int* in_sizes, int n_in,
                              void* d_out, int out_size, void* d_ws, size_t ws_size,
                              hipStream_t stream) {
  const float* x    = (const float*)d_in[0];
  const int*   eidx = (const int*)d_in[1];
  const int*   batch= (const int*)d_in[2];
  const float* W1 = (const float*)d_in[3];  const float* b1 = (const float*)d_in[4];
  const float* W2 = (const float*)d_in[5];  const float* b2 = (const float*)d_in[6];
  const float* W3 = (const float*)d_in[7];  const float* b3 = (const float*)d_in[8];
  const float* Wl1= (const float*)d_in[9];  const float* bl1= (const float*)d_in[10];
  const float* Wl2= (const float*)d_in[11]; const float* bl2= (const float*)d_in[12];
  const float* Wl3= (const float*)d_in[13]; const float* bl3= (const float*)d_in[14];
  const int* srcA = eidx;
  const int* dstA = eidx + NE;

  char* ws = (char*)d_ws;
  size_t off = 0;
  auto alloc = [&](size_t bytes) -> char* {
    char* p = ws + off;
    off = (off + bytes + 255) & ~(size_t)255;
    return p;
  };
  int*   counts  = (int*)  alloc((size_t)NN * 4);
  int*   row_ptr = (int*)  alloc((size_t)(NN + 1) * 4);
  int*   fill    = (int*)  alloc((size_t)NN * 4);
  float* dinv    = (float*)alloc((size_t)NN * 4);
  float* selfc   = (float*)alloc((size_t)NN * 4);
  Edge*  ecs     = (Edge*) alloc((size_t)NE * 8);
  unsigned short* aggxb = (unsigned short*)alloc((size_t)NNP * 32 * 2);
  unsigned short* W1t   = (unsigned short*)alloc((size_t)512 * 32 * 2);
  unsigned short* W2t   = (unsigned short*)alloc((size_t)416 * 512 * 2);
  unsigned short* W3t   = (unsigned short*)alloc((size_t)320 * 416 * 2);
  float* b1p     = (float*)alloc(512 * 4);
  unsigned short* T2 = (unsigned short*)alloc((size_t)NNP * 400 * 2);
  unsigned short* T3 = (unsigned short*)alloc((size_t)NNP * 304 * 2);
  float* gbuf    = (float*)alloc((size_t)NG * 300 * 4);
  float* a1      = (float*)alloc((size_t)NG * 200 * 4);
  float* a2      = (float*)alloc((size_t)NG * 100 * 4);
  float* logits  = (float*)alloc((size_t)NG * 6 * 4);

  // CSR build
  k_zero_i32<<<(NN + 255) / 256, 256, 0, stream>>>(counts, NN);
  k_count<<<(NE + 255) / 256, 256, 0, stream>>>(dstA, counts, NE);
  k_dinv<<<(NN + 255) / 256, 256, 0, stream>>>(counts, dinv, selfc, NN);
  k_scan<<<1, 1024, 0, stream>>>(counts, row_ptr, fill, NN);
  k_fill<<<(NE + 255) / 256, 256, 0, stream>>>(srcA, dstA, row_ptr, fill, dinv, ecs, NE);
  // weight prep
  k_prep_w1t<<<(512 * 32 + 255) / 256, 256, 0, stream>>>(W1, W1t);
  k_prep_w2t<<<(416 * 512 + 255) / 256, 256, 0, stream>>>(W2, W2t);
  k_prep_w3t<<<(320 * 416 + 255) / 256, 256, 0, stream>>>(W3, W3t);
  k_prep_b1<<<2, 256, 0, stream>>>(b1, b1p);
  // layers
  k_agg_x<<<(NNP + 7) / 8, 256, 0, stream>>>(x, row_ptr, ecs, selfc, aggxb, NN);
  k_fused12<<<NNP / 32, 256, 0, stream>>>(aggxb, W1t, b1p, W2t, T2);
  k_fused23<<<NNP / 32, 256, 0, stream>>>(T2, row_ptr, ecs, selfc, b2, W3t, T3);
  k_zero_f32<<<(NG * 300 + 255) / 256, 256, 0, stream>>>(gbuf, NG * 300);
  k_fused3m<<<NNP / 32, 256, 0, stream>>>(T3, row_ptr, ecs, selfc, b3, batch, gbuf);
  // head
  k_linear<<<(NG * 200 + 255) / 256, 256, 0, stream>>>(gbuf, Wl1, bl1, a1, NG, 200, 300, 1);
  k_linear<<<(NG * 100 + 255) / 256, 256, 0, stream>>>(a1, Wl2, bl2, a2, NG, 100, 200, 1);
  k_linear<<<(NG * 6 + 255) / 256, 256, 0, stream>>>(a2, Wl3, bl3, logits, NG, 6, 100, 0);
  k_softmax0<<<1, 256, 0, stream>>>(logits, (float*)d_out);
}

// Round 8
// 746.993 us; speedup vs baseline: 1.3718x; 1.3718x over previous
//
#include <hip/hip_runtime.h>
#include <hip/hip_bf16.h>

#define NN 50000
#define NNP 50016   // padded to 32*1563
#define NE 800000
#define NG 256
#define NB_SCAN 196 // ceil(NN/256)

typedef __attribute__((ext_vector_type(8))) short short8;
typedef __attribute__((ext_vector_type(8))) unsigned short ushort8;
typedef __attribute__((ext_vector_type(4))) float f32x4;

struct __align__(8) Edge { int s; float c; };

__device__ __forceinline__ float u2f(unsigned short u) {
  unsigned int t = ((unsigned int)u) << 16;
  return __builtin_bit_cast(float, t);
}
__device__ __forceinline__ unsigned short f2b(float f) {
  __hip_bfloat16 b = __float2bfloat16(f);
  return __builtin_bit_cast(unsigned short, b);
}
__device__ __forceinline__ f32x4 mfma_bf16(short8 a, short8 b, f32x4 c) {
  return __builtin_amdgcn_mfma_f32_16x16x32_bf16(a, b, c, 0, 0, 0);
}
__device__ __forceinline__ void fma8(float* acc, float c, const ushort8& v) {
  #pragma unroll
  for (int j = 0; j < 8; j++) acc[j] += c * u2f(v[j]);
}

// single-node depth-4 ring (R6 structure — R7 dual-ring proven neutral, reverted)
#define GRAMP(vv, cc, S, E0, CNT, BASE, STRIDE)                         \
  if ((S) < (CNT)) { Edge ed = ecs[(E0) + (S)]; cc = ed.c;              \
    vv = *(const ushort8*)((BASE) + (size_t)ed.s * (STRIDE) + cb); }    \
  else { cc = 0.f; vv = (ushort8)0; }

#define GSTEP(vv, cc, acc, EOFF, E0, E1, CNT, BASE, STRIDE)             \
  { ushort8 tv = vv; float tc = cc; int en = (E0) + (EOFF) + 4;         \
    if (en < (E1)) { Edge ed = ecs[en]; cc = ed.c;                      \
      vv = *(const ushort8*)((BASE) + (size_t)ed.s * (STRIDE) + cb); }  \
    if ((EOFF) < (CNT)) fma8(acc, tc, tv); }

// ---------------- CSR build ----------------
__global__ void k_zero_i32(int* __restrict__ p, int n) {
  int i = blockIdx.x * blockDim.x + threadIdx.x;
  if (i < n) p[i] = 0;
}
__global__ void k_count(const int* __restrict__ dst, int* __restrict__ counts, int E) {
  int e = blockIdx.x * blockDim.x + threadIdx.x;
  if (e < E) atomicAdd(&counts[dst[e]], 1);
}
__global__ void k_dinv(const int* __restrict__ counts, float* __restrict__ dinv,
                       float* __restrict__ selfc, int n) {
  int i = blockIdx.x * blockDim.x + threadIdx.x;
  if (i < n) {
    float d = (float)counts[i] + 1.0f;
    dinv[i]  = rsqrtf(d);
    selfc[i] = 1.0f / d;
  }
}

// ---- 3-kernel parallel exclusive scan (replaces 1-block serial k_scan) ----
__global__ void k_scan1(const int* __restrict__ counts, int* __restrict__ row_ptr,
                        int* __restrict__ bsum) {
  __shared__ int ws[4];
  int tid = threadIdx.x;
  int i = blockIdx.x * 256 + tid;
  int v = (i < NN) ? counts[i] : 0;
  int incl = v;
  #pragma unroll
  for (int off = 1; off < 64; off <<= 1) {
    int t = __shfl_up(incl, off, 64);
    if ((tid & 63) >= off) incl += t;
  }
  int wv = tid >> 6;
  if ((tid & 63) == 63) ws[wv] = incl;
  __syncthreads();
  if (tid == 0) {
    int s0 = ws[0], s1 = ws[1], s2 = ws[2], s3 = ws[3];
    ws[0] = 0; ws[1] = s0; ws[2] = s0 + s1; ws[3] = s0 + s1 + s2;
    bsum[blockIdx.x] = s0 + s1 + s2 + s3;
  }
  __syncthreads();
  if (i < NN) row_ptr[i] = ws[wv] + incl - v;
}
__global__ void k_scan2(int* __restrict__ bsum, int* __restrict__ row_ptr) {
  __shared__ int ws[4];
  int tid = threadIdx.x;
  int v = (tid < NB_SCAN) ? bsum[tid] : 0;
  int incl = v;
  #pragma unroll
  for (int off = 1; off < 64; off <<= 1) {
    int t = __shfl_up(incl, off, 64);
    if ((tid & 63) >= off) incl += t;
  }
  int wv = tid >> 6;
  if ((tid & 63) == 63) ws[wv] = incl;
  __syncthreads();
  if (tid == 0) {
    int s0 = ws[0], s1 = ws[1], s2 = ws[2], s3 = ws[3];
    ws[0] = 0; ws[1] = s0; ws[2] = s0 + s1; ws[3] = s0 + s1 + s2;
    row_ptr[NN] = s0 + s1 + s2 + s3;
  }
  __syncthreads();
  if (tid < NB_SCAN) bsum[tid] = ws[wv] + incl - v;
}
__global__ void k_scan3(const int* __restrict__ bsum, int* __restrict__ row_ptr,
                        int* __restrict__ fill) {
  int i = blockIdx.x * 256 + threadIdx.x;
  if (i < NN) {
    row_ptr[i] += bsum[blockIdx.x];
    fill[i] = 0;
  }
}

__global__ void k_fill(const int* __restrict__ src, const int* __restrict__ dst,
                       const int* __restrict__ row_ptr, int* __restrict__ fill,
                       const float* __restrict__ dinv, Edge* __restrict__ ecs, int E) {
  int e = blockIdx.x * blockDim.x + threadIdx.x;
  if (e < E) {
    int s = src[e], d = dst[e];
    int pos = row_ptr[d] + atomicAdd(&fill[d], 1);
    Edge ed; ed.s = s; ed.c = dinv[s] * dinv[d];
    ecs[pos] = ed;
  }
}

// ---- fused weight prep: W1t/W2t/W3t bf16-transpose-pad + b1p + gbuf zero ----
#define PR_W1 16384
#define PR_W2 212992
#define PR_W3 133120
#define PR_B1 512
#define PR_GB 76800
__global__ void k_prep_all(const float* __restrict__ W1, const float* __restrict__ W2,
                           const float* __restrict__ W3, const float* __restrict__ b1,
                           unsigned short* __restrict__ W1t, unsigned short* __restrict__ W2t,
                           unsigned short* __restrict__ W3t, float* __restrict__ b1p,
                           float* __restrict__ gbuf) {
  int idx = blockIdx.x * blockDim.x + threadIdx.x;
  if (idx < PR_W1) {
    int n = idx >> 5, k = idx & 31;
    W1t[idx] = f2b((n < 500 && k < 19) ? W1[k * 500 + n] : 0.f);
    return;
  }
  idx -= PR_W1;
  if (idx < PR_W2) {
    int n = idx >> 9, k = idx & 511;
    W2t[idx] = f2b((n < 400 && k < 500) ? W2[k * 400 + n] : 0.f);
    return;
  }
  idx -= PR_W2;
  if (idx < PR_W3) {
    int n = idx / 416, k = idx - n * 416;
    W3t[idx] = f2b((n < 300 && k < 400) ? W3[k * 300 + n] : 0.f);
    return;
  }
  idx -= PR_W3;
  if (idx < PR_B1) { b1p[idx] = (idx < 500) ? b1[idx] : 0.f; return; }
  idx -= PR_B1;
  if (idx < PR_GB) gbuf[idx] = 0.f;
}

// ---------------- layer-1 aggregation of x -> bf16 [NNP][32] ----------------
__global__ __launch_bounds__(256, 4) void k_agg_x(
    const float* __restrict__ x, const int* __restrict__ row_ptr,
    const Edge* __restrict__ ecs, const float* __restrict__ selfc,
    unsigned short* __restrict__ aggxb, int n) {
  int tid  = threadIdx.x;
  int node = blockIdx.x * 8 + (tid >> 5);
  int lane = tid & 31;
  if (node >= NNP) return;
  float acc = 0.f;
  if (node < n && lane < 19) {
    int e0 = row_ptr[node], e1 = row_ptr[node + 1];
    int cnt = e1 - e0;
    float v0 = 0.f, v1 = 0.f, v2 = 0.f, v3 = 0.f;
    float c0 = 0.f, c1 = 0.f, c2 = 0.f, c3 = 0.f;
    if (cnt > 0) { Edge ed = ecs[e0];     c0 = ed.c; v0 = x[(size_t)ed.s * 19 + lane]; }
    if (cnt > 1) { Edge ed = ecs[e0 + 1]; c1 = ed.c; v1 = x[(size_t)ed.s * 19 + lane]; }
    if (cnt > 2) { Edge ed = ecs[e0 + 2]; c2 = ed.c; v2 = x[(size_t)ed.s * 19 + lane]; }
    if (cnt > 3) { Edge ed = ecs[e0 + 3]; c3 = ed.c; v3 = x[(size_t)ed.s * 19 + lane]; }
    for (int e = 0; e < cnt; e += 4) {
      float tv, tc; int en;
      tv = v0; tc = c0; en = e0 + e + 4;
      if (en < e1) { Edge ed = ecs[en]; c0 = ed.c; v0 = x[(size_t)ed.s * 19 + lane]; }
      if (e < cnt) acc += tc * tv;
      tv = v1; tc = c1; en = e0 + e + 5;
      if (en < e1) { Edge ed = ecs[en]; c1 = ed.c; v1 = x[(size_t)ed.s * 19 + lane]; }
      if (e + 1 < cnt) acc += tc * tv;
      tv = v2; tc = c2; en = e0 + e + 6;
      if (en < e1) { Edge ed = ecs[en]; c2 = ed.c; v2 = x[(size_t)ed.s * 19 + lane]; }
      if (e + 2 < cnt) acc += tc * tv;
      tv = v3; tc = c3; en = e0 + e + 7;
      if (en < e1) { Edge ed = ecs[en]; c3 = ed.c; v3 = x[(size_t)ed.s * 19 + lane]; }
      if (e + 3 < cnt) acc += tc * tv;
    }
    acc += selfc[node] * x[(size_t)node * 19 + lane];
  }
  aggxb[(size_t)node * 32 + lane] = (node < n && lane < 19) ? f2b(acc) : (unsigned short)0;
}

// ---- fused layer1+2: T2 = (relu(aggx@W1+b1)) @ W2, MFMA, H1 tile in LDS ----
__global__ __launch_bounds__(256) void k_fused12(
    const unsigned short* __restrict__ aggxb, const unsigned short* __restrict__ W1t,
    const float* __restrict__ b1p, const unsigned short* __restrict__ W2t,
    unsigned short* __restrict__ T2) {
  __shared__ unsigned short Hs[32][520];
  int tid = threadIdx.x;
  int lane = tid & 63, wv = tid >> 6;
  int l15 = lane & 15, quad = lane >> 4;
  int r0 = blockIdx.x * 32;
  for (int t = wv; t < 64; t += 4) {
    int rt = t & 1, ct = t >> 1;
    short8 a = *(const short8*)(aggxb + (size_t)(r0 + rt * 16 + l15) * 32 + quad * 8);
    short8 b = *(const short8*)(W1t + (size_t)(ct * 16 + l15) * 32 + quad * 8);
    f32x4 c = {0.f, 0.f, 0.f, 0.f};
    c = mfma_bf16(a, b, c);
    int col = ct * 16 + l15;
    float bias = b1p[col];
    int rbase = rt * 16 + quad * 4;
    #pragma unroll
    for (int r = 0; r < 4; r++)
      Hs[rbase + r][col] = f2b(fmaxf(c[r] + bias, 0.f));
  }
  __syncthreads();
  int rt = wv >> 1, p = wv & 1;
  f32x4 acc[13];
  #pragma unroll
  for (int j = 0; j < 13; j++) acc[j] = (f32x4){0.f, 0.f, 0.f, 0.f};
  for (int k0 = 0; k0 < 512; k0 += 32) {
    short8 a = *(const short8*)&Hs[rt * 16 + l15][k0 + quad * 8];
    #pragma unroll
    for (int j = 0; j < 13; j++) {
      int n = (p + 2 * j) * 16 + l15;
      short8 b = *(const short8*)(W2t + (size_t)n * 512 + k0 + quad * 8);
      acc[j] = mfma_bf16(a, b, acc[j]);
    }
  }
  int rr = r0 + rt * 16 + quad * 4;
  #pragma unroll
  for (int j = 0; j < 13; j++) {
    int n = (p + 2 * j) * 16 + l15;
    if (n < 400) {
      #pragma unroll
      for (int r = 0; r < 4; r++) {
        int row = rr + r;
        if (row < NN) T2[(size_t)row * 400 + n] = f2b(acc[j][r]);
      }
    }
  }
}

// ---- fused layer2 agg + layer3 linear: T3 = relu(agg(T2)+b2) @ W3 (MFMA) ----
// phase A: wave-per-node single depth-4 ring (R6 structure, Edge loads)
__global__ __launch_bounds__(256, 4) void k_fused23(
    const unsigned short* __restrict__ T2, const int* __restrict__ row_ptr,
    const Edge* __restrict__ ecs, const float* __restrict__ selfc,
    const float* __restrict__ b2, const unsigned short* __restrict__ W3t,
    unsigned short* __restrict__ T3) {
  __shared__ unsigned short Hs[32][424];
  int tid = threadIdx.x;
  int lane = tid & 63, wv = tid >> 6;
  int l15 = lane & 15, quad = lane >> 4;
  int r0 = blockIdx.x * 32;
  bool act = lane < 50;
  int cb = lane * 8;
  for (int i = 0; i < 8; i++) {
    int nl = wv + 4 * i;
    int node = r0 + nl;
    ushort8 out = (ushort8)0;
    if (node < NN && act) {
      float acc[8];
      #pragma unroll
      for (int j = 0; j < 8; j++) acc[j] = 0.f;
      int e0 = row_ptr[node], e1 = row_ptr[node + 1];
      int cnt = e1 - e0;
      ushort8 v0, v1, v2, v3;
      float c0, c1, c2, c3;
      GRAMP(v0, c0, 0, e0, cnt, T2, 400)
      GRAMP(v1, c1, 1, e0, cnt, T2, 400)
      GRAMP(v2, c2, 2, e0, cnt, T2, 400)
      GRAMP(v3, c3, 3, e0, cnt, T2, 400)
      for (int e = 0; e < cnt; e += 4) {
        GSTEP(v0, c0, acc, e + 0, e0, e1, cnt, T2, 400)
        GSTEP(v1, c1, acc, e + 1, e0, e1, cnt, T2, 400)
        GSTEP(v2, c2, acc, e + 2, e0, e1, cnt, T2, 400)
        GSTEP(v3, c3, acc, e + 3, e0, e1, cnt, T2, 400)
      }
      ushort8 sv = *(const ushort8*)(T2 + (size_t)node * 400 + cb);
      float sc = selfc[node];
      #pragma unroll
      for (int j = 0; j < 8; j++)
        out[j] = f2b(fmaxf(acc[j] + sc * u2f(sv[j]) + b2[cb + j], 0.f));
    }
    if (lane < 52) *(ushort8*)&Hs[nl][cb] = out;
  }
  __syncthreads();
  int rt = wv >> 1, p = wv & 1;
  f32x4 acc[10];
  #pragma unroll
  for (int j = 0; j < 10; j++) acc[j] = (f32x4){0.f, 0.f, 0.f, 0.f};
  for (int k0 = 0; k0 < 416; k0 += 32) {
    short8 a = *(const short8*)&Hs[rt * 16 + l15][k0 + quad * 8];
    #pragma unroll
    for (int j = 0; j < 10; j++) {
      int n = (p + 2 * j) * 16 + l15;
      short8 b = *(const short8*)(W3t + (size_t)n * 416 + k0 + quad * 8);
      acc[j] = mfma_bf16(a, b, acc[j]);
    }
  }
  int rr = r0 + rt * 16 + quad * 4;
  #pragma unroll
  for (int j = 0; j < 10; j++) {
    int n = (p + 2 * j) * 16 + l15;
    if (n < 300) {
      #pragma unroll
      for (int r = 0; r < 4; r++) {
        int row = rr + r;
        if (row < NN) T3[(size_t)row * 304 + n] = f2b(acc[j][r]);
      }
    }
  }
}

// ---- fused layer3 agg + bias + relu + per-graph max pool (sorted batch) ----
__global__ __launch_bounds__(256, 4) void k_fused3m(
    const unsigned short* __restrict__ T3, const int* __restrict__ row_ptr,
    const Edge* __restrict__ ecs, const float* __restrict__ selfc,
    const float* __restrict__ b3, const int* __restrict__ batch,
    float* __restrict__ gbuf) {
  __shared__ unsigned int lmax[4][304];
  int tid = threadIdx.x;
  int lane = tid & 63, wv = tid >> 6;
  int r0 = blockIdx.x * 32;
  int g0 = batch[r0];
  for (int i = tid; i < 4 * 304; i += 256) ((unsigned int*)lmax)[i] = 0u;
  __syncthreads();
  bool act = lane < 38;
  int cb = lane * 8;
  for (int i = 0; i < 8; i++) {
    int node = r0 + wv * 8 + i;
    if (node >= NN) break;
    if (act) {
      float acc[8];
      #pragma unroll
      for (int j = 0; j < 8; j++) acc[j] = 0.f;
      int e0 = row_ptr[node], e1 = row_ptr[node + 1];
      int cnt = e1 - e0;
      ushort8 v0, v1, v2, v3;
      float c0, c1, c2, c3;
      GRAMP(v0, c0, 0, e0, cnt, T3, 304)
      GRAMP(v1, c1, 1, e0, cnt, T3, 304)
      GRAMP(v2, c2, 2, e0, cnt, T3, 304)
      GRAMP(v3, c3, 3, e0, cnt, T3, 304)
      for (int e = 0; e < cnt; e += 4) {
        GSTEP(v0, c0, acc, e + 0, e0, e1, cnt, T3, 304)
        GSTEP(v1, c1, acc, e + 1, e0, e1, cnt, T3, 304)
        GSTEP(v2, c2, acc, e + 2, e0, e1, cnt, T3, 304)
        GSTEP(v3, c3, acc, e + 3, e0, e1, cnt, T3, 304)
      }
      ushort8 sv = *(const ushort8*)(T3 + (size_t)node * 304 + cb);
      float sc = selfc[node];
      int slot = batch[node] - g0;
      #pragma unroll
      for (int j = 0; j < 8; j++) {
        int c = cb + j;
        if (c < 300) {
          float v = fmaxf(acc[j] + sc * u2f(sv[j]) + b3[c], 0.f);
          unsigned int uv = __float_as_uint(v);
          if (slot < 4) atomicMax(&lmax[slot][c], uv);
          else atomicMax((unsigned int*)&gbuf[(size_t)(g0 + slot) * 300 + c], uv);
        }
      }
    }
  }
  __syncthreads();
  for (int i = tid; i < 4 * 304; i += 256) {
    int s = i / 304, c = i - s * 304;
    unsigned int uv = lmax[s][c];
    int g = g0 + s;
    if (c < 300 && uv != 0u && g < NG)
      atomicMax((unsigned int*)&gbuf[(size_t)g * 300 + c], uv);
  }
}

// ---- fused head MLP: per-graph 300->200->100->6 (one block per graph) ----
__global__ __launch_bounds__(256) void k_head(
    const float* __restrict__ gbuf, const float* __restrict__ Wl1,
    const float* __restrict__ bl1, const float* __restrict__ Wl2,
    const float* __restrict__ bl2, const float* __restrict__ Wl3,
    const float* __restrict__ bl3, float* __restrict__ logits) {
  __shared__ float g[304], a1[200], a2[112];
  int gid = blockIdx.x, tid = threadIdx.x;
  for (int i = tid; i < 300; i += 256) g[i] = gbuf[(size_t)gid * 300 + i];
  __syncthreads();
  if (tid < 200) {
    float acc = bl1[tid];
    for (int k = 0; k < 300; k++) acc += g[k] * Wl1[k * 200 + tid];
    a1[tid] = fmaxf(acc, 0.f);
  }
  __syncthreads();
  if (tid < 100) {
    float acc = bl2[tid];
    for (int k = 0; k < 200; k++) acc += a1[k] * Wl2[k * 100 + tid];
    a2[tid] = fmaxf(acc, 0.f);
  }
  __syncthreads();
  if (tid < 6) {
    float acc = bl3[tid];
    for (int k = 0; k < 100; k++) acc += a2[k] * Wl3[k * 6 + tid];
    logits[gid * 6 + tid] = acc;
  }
}

__global__ void k_softmax0(const float* __restrict__ logits, float* __restrict__ out) {
  __shared__ float cmax[6], csum[6];
  int g = threadIdx.x;
  if (g < 6) {
    float m = -1e30f;
    for (int i = 0; i < NG; i++) m = fmaxf(m, logits[i * 6 + g]);
    float s = 0.f;
    for (int i = 0; i < NG; i++) s += expf(logits[i * 6 + g] - m);
    cmax[g] = m; csum[g] = s;
  }
  __syncthreads();
  for (int c = 0; c < 6; c++)
    out[g * 6 + c] = expf(logits[g * 6 + c] - cmax[c]) / csum[c];
}

extern "C" void kernel_launch(void* const* d_in, const int* in_sizes, int n_in,
                              void* d_out, int out_size, void* d_ws, size_t ws_size,
                              hipStream_t stream) {
  const float* x    = (const float*)d_in[0];
  const int*   eidx = (const int*)d_in[1];
  const int*   batch= (const int*)d_in[2];
  const float* W1 = (const float*)d_in[3];  const float* b1 = (const float*)d_in[4];
  const float* W2 = (const float*)d_in[5];  const float* b2 = (const float*)d_in[6];
  const float* W3 = (const float*)d_in[7];  const float* b3 = (const float*)d_in[8];
  const float* Wl1= (const float*)d_in[9];  const float* bl1= (const float*)d_in[10];
  const float* Wl2= (const float*)d_in[11]; const float* bl2= (const float*)d_in[12];
  const float* Wl3= (const float*)d_in[13]; const float* bl3= (const float*)d_in[14];
  const int* srcA = eidx;
  const int* dstA = eidx + NE;

  char* ws = (char*)d_ws;
  size_t off = 0;
  auto alloc = [&](size_t bytes) -> char* {
    char* p = ws + off;
    off = (off + bytes + 255) & ~(size_t)255;
    return p;
  };
  int*   counts  = (int*)  alloc((size_t)NN * 4);
  int*   row_ptr = (int*)  alloc((size_t)(NN + 1) * 4);
  int*   fill    = (int*)  alloc((size_t)NN * 4);
  int*   bsum    = (int*)  alloc(256 * 4);
  float* dinv    = (float*)alloc((size_t)NN * 4);
  float* selfc   = (float*)alloc((size_t)NN * 4);
  Edge*  ecs     = (Edge*) alloc((size_t)NE * 8);
  unsigned short* aggxb = (unsigned short*)alloc((size_t)NNP * 32 * 2);
  unsigned short* W1t   = (unsigned short*)alloc((size_t)512 * 32 * 2);
  unsigned short* W2t   = (unsigned short*)alloc((size_t)416 * 512 * 2);
  unsigned short* W3t   = (unsigned short*)alloc((size_t)320 * 416 * 2);
  float* b1p     = (float*)alloc(512 * 4);
  unsigned short* T2 = (unsigned short*)alloc((size_t)NNP * 400 * 2);
  unsigned short* T3 = (unsigned short*)alloc((size_t)NNP * 304 * 2);
  float* gbuf    = (float*)alloc((size_t)NG * 300 * 4);
  float* logits  = (float*)alloc((size_t)NG * 6 * 4);

  // CSR build (parallel scan)
  k_zero_i32<<<(NN + 255) / 256, 256, 0, stream>>>(counts, NN);
  k_count<<<(NE + 255) / 256, 256, 0, stream>>>(dstA, counts, NE);
  k_dinv<<<(NN + 255) / 256, 256, 0, stream>>>(counts, dinv, selfc, NN);
  k_scan1<<<NB_SCAN, 256, 0, stream>>>(counts, row_ptr, bsum);
  k_scan2<<<1, 256, 0, stream>>>(bsum, row_ptr);
  k_scan3<<<NB_SCAN, 256, 0, stream>>>(bsum, row_ptr, fill);
  k_fill<<<(NE + 255) / 256, 256, 0, stream>>>(srcA, dstA, row_ptr, fill, dinv, ecs, NE);
  // fused weight prep + gbuf zero
  k_prep_all<<<(PR_W1 + PR_W2 + PR_W3 + PR_B1 + PR_GB + 255) / 256, 256, 0, stream>>>(
      W1, W2, W3, b1, W1t, W2t, W3t, b1p, gbuf);
  // layers
  k_agg_x<<<(NNP + 7) / 8, 256, 0, stream>>>(x, row_ptr, ecs, selfc, aggxb, NN);
  k_fused12<<<NNP / 32, 256, 0, stream>>>(aggxb, W1t, b1p, W2t, T2);
  k_fused23<<<NNP / 32, 256, 0, stream>>>(T2, row_ptr, ecs, selfc, b2, W3t, T3);
  k_fused3m<<<NNP / 32, 256, 0, stream>>>(T3, row_ptr, ecs, selfc, b3, batch, gbuf);
  // fused head + softmax over dim 0
  k_head<<<NG, 256, 0, stream>>>(gbuf, Wl1, bl1, Wl2, bl2, Wl3, bl3, logits);
  k_softmax0<<<1, 256, 0, stream>>>(logits, (float*)d_out);
}

// Round 9
// 718.519 us; speedup vs baseline: 1.4262x; 1.0396x over previous
//
#include <hip/hip_runtime.h>
#include <hip/hip_bf16.h>

#define NN 50000
#define NNP 50016   // padded to 32*1563
#define NE 800000
#define NG 256
#define NB_SCAN 196 // ceil(NN/256)

typedef __attribute__((ext_vector_type(8))) short short8;
typedef __attribute__((ext_vector_type(8))) unsigned short ushort8;
typedef __attribute__((ext_vector_type(4))) float f32x4;

struct __align__(8) Edge { int s; float c; };

__device__ __forceinline__ float u2f(unsigned short u) {
  unsigned int t = ((unsigned int)u) << 16;
  return __builtin_bit_cast(float, t);
}
__device__ __forceinline__ unsigned short f2b(float f) {
  __hip_bfloat16 b = __float2bfloat16(f);
  return __builtin_bit_cast(unsigned short, b);
}
__device__ __forceinline__ f32x4 mfma_bf16(short8 a, short8 b, f32x4 c) {
  return __builtin_amdgcn_mfma_f32_16x16x32_bf16(a, b, c, 0, 0, 0);
}
__device__ __forceinline__ void fma8(float* acc, float c, const ushort8& v) {
  #pragma unroll
  for (int j = 0; j < 8; j++) acc[j] += c * u2f(v[j]);
}

// single-node depth-4 ring (R6 structure; R7 dual-ring was neutral)
#define GRAMP(vv, cc, S, E0, CNT, BASE, STRIDE)                         \
  if ((S) < (CNT)) { Edge ed = ecs[(E0) + (S)]; cc = ed.c;              \
    vv = *(const ushort8*)((BASE) + (size_t)ed.s * (STRIDE) + cb); }    \
  else { cc = 0.f; vv = (ushort8)0; }

#define GSTEP(vv, cc, acc, EOFF, E0, E1, CNT, BASE, STRIDE)             \
  { ushort8 tv = vv; float tc = cc; int en = (E0) + (EOFF) + 4;         \
    if (en < (E1)) { Edge ed = ecs[en]; cc = ed.c;                      \
      vv = *(const ushort8*)((BASE) + (size_t)ed.s * (STRIDE) + cb); }  \
    if ((EOFF) < (CNT)) fma8(acc, tc, tv); }

// ---------------- CSR build ----------------
__global__ void k_zero_i32(int* __restrict__ p, int n) {
  int i = blockIdx.x * blockDim.x + threadIdx.x;
  if (i < n) p[i] = 0;
}
__global__ void k_count(const int* __restrict__ dst, int* __restrict__ counts, int E) {
  int e = blockIdx.x * blockDim.x + threadIdx.x;
  if (e < E) atomicAdd(&counts[dst[e]], 1);
}
__global__ void k_dinv(const int* __restrict__ counts, float* __restrict__ dinv,
                       float* __restrict__ selfc, int n) {
  int i = blockIdx.x * blockDim.x + threadIdx.x;
  if (i < n) {
    float d = (float)counts[i] + 1.0f;
    dinv[i]  = rsqrtf(d);
    selfc[i] = 1.0f / d;
  }
}

// ---- 3-kernel parallel exclusive scan ----
__global__ void k_scan1(const int* __restrict__ counts, int* __restrict__ row_ptr,
                        int* __restrict__ bsum) {
  __shared__ int ws[4];
  int tid = threadIdx.x;
  int i = blockIdx.x * 256 + tid;
  int v = (i < NN) ? counts[i] : 0;
  int incl = v;
  #pragma unroll
  for (int off = 1; off < 64; off <<= 1) {
    int t = __shfl_up(incl, off, 64);
    if ((tid & 63) >= off) incl += t;
  }
  int wv = tid >> 6;
  if ((tid & 63) == 63) ws[wv] = incl;
  __syncthreads();
  if (tid == 0) {
    int s0 = ws[0], s1 = ws[1], s2 = ws[2], s3 = ws[3];
    ws[0] = 0; ws[1] = s0; ws[2] = s0 + s1; ws[3] = s0 + s1 + s2;
    bsum[blockIdx.x] = s0 + s1 + s2 + s3;
  }
  __syncthreads();
  if (i < NN) row_ptr[i] = ws[wv] + incl - v;
}
__global__ void k_scan2(int* __restrict__ bsum, int* __restrict__ row_ptr) {
  __shared__ int ws[4];
  int tid = threadIdx.x;
  int v = (tid < NB_SCAN) ? bsum[tid] : 0;
  int incl = v;
  #pragma unroll
  for (int off = 1; off < 64; off <<= 1) {
    int t = __shfl_up(incl, off, 64);
    if ((tid & 63) >= off) incl += t;
  }
  int wv = tid >> 6;
  if ((tid & 63) == 63) ws[wv] = incl;
  __syncthreads();
  if (tid == 0) {
    int s0 = ws[0], s1 = ws[1], s2 = ws[2], s3 = ws[3];
    ws[0] = 0; ws[1] = s0; ws[2] = s0 + s1; ws[3] = s0 + s1 + s2;
    row_ptr[NN] = s0 + s1 + s2 + s3;
  }
  __syncthreads();
  if (tid < NB_SCAN) bsum[tid] = ws[wv] + incl - v;
}
__global__ void k_scan3(const int* __restrict__ bsum, int* __restrict__ row_ptr,
                        int* __restrict__ fill) {
  int i = blockIdx.x * 256 + threadIdx.x;
  if (i < NN) {
    row_ptr[i] += bsum[blockIdx.x];
    fill[i] = 0;
  }
}

__global__ void k_fill(const int* __restrict__ src, const int* __restrict__ dst,
                       const int* __restrict__ row_ptr, int* __restrict__ fill,
                       const float* __restrict__ dinv, Edge* __restrict__ ecs, int E) {
  int e = blockIdx.x * blockDim.x + threadIdx.x;
  if (e < E) {
    int s = src[e], d = dst[e];
    int pos = row_ptr[d] + atomicAdd(&fill[d], 1);
    Edge ed; ed.s = s; ed.c = dinv[s] * dinv[d];
    ecs[pos] = ed;
  }
}

// ---- fused weight prep ----
// W1t: [n][32] n-major (phase A, small). W2c: [16 chunk][416 n][32 kk],
// W3c: [13 chunk][320 n][32 kk] — chunk-major so per-chunk LDS staging reads
// are perfectly sequential (R8: n-major streaming hit 16-line/inst L1-miss serialization).
#define PR_W1 16384
#define PR_W2 212992
#define PR_W3 133120
#define PR_B1 512
#define PR_GB 76800
__global__ void k_prep_all(const float* __restrict__ W1, const float* __restrict__ W2,
                           const float* __restrict__ W3, const float* __restrict__ b1,
                           unsigned short* __restrict__ W1t, unsigned short* __restrict__ W2c,
                           unsigned short* __restrict__ W3c, float* __restrict__ b1p,
                           float* __restrict__ gbuf) {
  int idx = blockIdx.x * blockDim.x + threadIdx.x;
  if (idx < PR_W1) {
    int n = idx >> 5, k = idx & 31;
    W1t[idx] = f2b((n < 500 && k < 19) ? W1[k * 500 + n] : 0.f);
    return;
  }
  idx -= PR_W1;
  if (idx < PR_W2) {
    int n = idx >> 9, k = idx & 511;
    float v = (n < 400 && k < 500) ? W2[k * 400 + n] : 0.f;
    int ch = k >> 5, kk = k & 31;
    W2c[((size_t)ch * 416 + n) * 32 + kk] = f2b(v);
    return;
  }
  idx -= PR_W2;
  if (idx < PR_W3) {
    int n = idx / 416, k = idx - n * 416;
    float v = (n < 300 && k < 400) ? W3[k * 300 + n] : 0.f;
    int ch = k >> 5, kk = k & 31;
    W3c[((size_t)ch * 320 + n) * 32 + kk] = f2b(v);
    return;
  }
  idx -= PR_W3;
  if (idx < PR_B1) { b1p[idx] = (idx < 500) ? b1[idx] : 0.f; return; }
  idx -= PR_B1;
  if (idx < PR_GB) gbuf[idx] = 0.f;
}

// ---------------- layer-1 aggregation of x -> bf16 [NNP][32] ----------------
__global__ __launch_bounds__(256, 4) void k_agg_x(
    const float* __restrict__ x, const int* __restrict__ row_ptr,
    const Edge* __restrict__ ecs, const float* __restrict__ selfc,
    unsigned short* __restrict__ aggxb, int n) {
  int tid  = threadIdx.x;
  int node = blockIdx.x * 8 + (tid >> 5);
  int lane = tid & 31;
  if (node >= NNP) return;
  float acc = 0.f;
  if (node < n && lane < 19) {
    int e0 = row_ptr[node], e1 = row_ptr[node + 1];
    int cnt = e1 - e0;
    float v0 = 0.f, v1 = 0.f, v2 = 0.f, v3 = 0.f;
    float c0 = 0.f, c1 = 0.f, c2 = 0.f, c3 = 0.f;
    if (cnt > 0) { Edge ed = ecs[e0];     c0 = ed.c; v0 = x[(size_t)ed.s * 19 + lane]; }
    if (cnt > 1) { Edge ed = ecs[e0 + 1]; c1 = ed.c; v1 = x[(size_t)ed.s * 19 + lane]; }
    if (cnt > 2) { Edge ed = ecs[e0 + 2]; c2 = ed.c; v2 = x[(size_t)ed.s * 19 + lane]; }
    if (cnt > 3) { Edge ed = ecs[e0 + 3]; c3 = ed.c; v3 = x[(size_t)ed.s * 19 + lane]; }
    for (int e = 0; e < cnt; e += 4) {
      float tv, tc; int en;
      tv = v0; tc = c0; en = e0 + e + 4;
      if (en < e1) { Edge ed = ecs[en]; c0 = ed.c; v0 = x[(size_t)ed.s * 19 + lane]; }
      if (e < cnt) acc += tc * tv;
      tv = v1; tc = c1; en = e0 + e + 5;
      if (en < e1) { Edge ed = ecs[en]; c1 = ed.c; v1 = x[(size_t)ed.s * 19 + lane]; }
      if (e + 1 < cnt) acc += tc * tv;
      tv = v2; tc = c2; en = e0 + e + 6;
      if (en < e1) { Edge ed = ecs[en]; c2 = ed.c; v2 = x[(size_t)ed.s * 19 + lane]; }
      if (e + 2 < cnt) acc += tc * tv;
      tv = v3; tc = c3; en = e0 + e + 7;
      if (en < e1) { Edge ed = ecs[en]; c3 = ed.c; v3 = x[(size_t)ed.s * 19 + lane]; }
      if (e + 3 < cnt) acc += tc * tv;
    }
    acc += selfc[node] * x[(size_t)node * 19 + lane];
  }
  aggxb[(size_t)node * 32 + lane] = (node < n && lane < 19) ? f2b(acc) : (unsigned short)0;
}

// ---- fused layer1+2: T2 = (relu(aggx@W1+b1)) @ W2, MFMA ----
// phase B: W2 chunk staged in LDS (34-short padded rows -> 2-way banks, free)
__global__ __launch_bounds__(256) void k_fused12(
    const unsigned short* __restrict__ aggxb, const unsigned short* __restrict__ W1t,
    const float* __restrict__ b1p, const unsigned short* __restrict__ W2c,
    unsigned short* __restrict__ T2) {
  __shared__ unsigned short Hs[32][520];   // 33280 B
  __shared__ unsigned short Ws[416 * 34];  // 28288 B
  int tid = threadIdx.x;
  int lane = tid & 63, wv = tid >> 6;
  int l15 = lane & 15, quad = lane >> 4;
  int r0 = blockIdx.x * 32;
  // phase A: Hs = relu(aggx@W1 + b1)
  for (int t = wv; t < 64; t += 4) {
    int rt = t & 1, ct = t >> 1;
    short8 a = *(const short8*)(aggxb + (size_t)(r0 + rt * 16 + l15) * 32 + quad * 8);
    short8 b = *(const short8*)(W1t + (size_t)(ct * 16 + l15) * 32 + quad * 8);
    f32x4 c = {0.f, 0.f, 0.f, 0.f};
    c = mfma_bf16(a, b, c);
    int col = ct * 16 + l15;
    float bias = b1p[col];
    int rbase = rt * 16 + quad * 4;
    #pragma unroll
    for (int r = 0; r < 4; r++)
      Hs[rbase + r][col] = f2b(fmaxf(c[r] + bias, 0.f));
  }
  // phase B: 16 chunks of K=32, W2 chunk staged in LDS per iteration
  int rt = wv >> 1, p = wv & 1;
  f32x4 acc[13];
  #pragma unroll
  for (int j = 0; j < 13; j++) acc[j] = (f32x4){0.f, 0.f, 0.f, 0.f};
  for (int ch = 0; ch < 16; ch++) {
    __syncthreads();   // Ws consumed by previous iter (first: Hs written)
    const unsigned short* src = W2c + (size_t)ch * (416 * 32);
    #pragma unroll
    for (int it = 0; it < 7; it++) {
      int idx = it * 256 + tid;
      if (idx < 1664) {
        ushort8 v = *(const ushort8*)(src + idx * 8);
        int n = idx >> 2, part = idx & 3;
        *(ushort8*)&Ws[n * 34 + part * 8] = v;
      }
    }
    __syncthreads();
    short8 a = *(const short8*)&Hs[rt * 16 + l15][ch * 32 + quad * 8];
    #pragma unroll
    for (int j = 0; j < 13; j++) {
      int n = (p + 2 * j) * 16 + l15;
      short8 b = *(const short8*)&Ws[n * 34 + quad * 8];
      acc[j] = mfma_bf16(a, b, acc[j]);
    }
  }
  int rr = r0 + rt * 16 + quad * 4;
  #pragma unroll
  for (int j = 0; j < 13; j++) {
    int n = (p + 2 * j) * 16 + l15;
    if (n < 400) {
      #pragma unroll
      for (int r = 0; r < 4; r++) {
        int row = rr + r;
        if (row < NN) T2[(size_t)row * 400 + n] = f2b(acc[j][r]);
      }
    }
  }
}

// ---- fused layer2 agg + layer3 linear: T3 = relu(agg(T2)+b2) @ W3 (MFMA) ----
__global__ __launch_bounds__(256, 4) void k_fused23(
    const unsigned short* __restrict__ T2, const int* __restrict__ row_ptr,
    const Edge* __restrict__ ecs, const float* __restrict__ selfc,
    const float* __restrict__ b2, const unsigned short* __restrict__ W3c,
    unsigned short* __restrict__ T3) {
  __shared__ unsigned short Hs[32][424];   // 27136 B
  __shared__ unsigned short Ws[320 * 34];  // 21760 B
  int tid = threadIdx.x;
  int lane = tid & 63, wv = tid >> 6;
  int l15 = lane & 15, quad = lane >> 4;
  int r0 = blockIdx.x * 32;
  bool act = lane < 50;
  int cb = lane * 8;
  for (int i = 0; i < 8; i++) {
    int nl = wv + 4 * i;
    int node = r0 + nl;
    ushort8 out = (ushort8)0;
    if (node < NN && act) {
      float acc[8];
      #pragma unroll
      for (int j = 0; j < 8; j++) acc[j] = 0.f;
      int e0 = row_ptr[node], e1 = row_ptr[node + 1];
      int cnt = e1 - e0;
      ushort8 v0, v1, v2, v3;
      float c0, c1, c2, c3;
      GRAMP(v0, c0, 0, e0, cnt, T2, 400)
      GRAMP(v1, c1, 1, e0, cnt, T2, 400)
      GRAMP(v2, c2, 2, e0, cnt, T2, 400)
      GRAMP(v3, c3, 3, e0, cnt, T2, 400)
      for (int e = 0; e < cnt; e += 4) {
        GSTEP(v0, c0, acc, e + 0, e0, e1, cnt, T2, 400)
        GSTEP(v1, c1, acc, e + 1, e0, e1, cnt, T2, 400)
        GSTEP(v2, c2, acc, e + 2, e0, e1, cnt, T2, 400)
        GSTEP(v3, c3, acc, e + 3, e0, e1, cnt, T2, 400)
      }
      ushort8 sv = *(const ushort8*)(T2 + (size_t)node * 400 + cb);
      float sc = selfc[node];
      #pragma unroll
      for (int j = 0; j < 8; j++)
        out[j] = f2b(fmaxf(acc[j] + sc * u2f(sv[j]) + b2[cb + j], 0.f));
    }
    if (lane < 52) *(ushort8*)&Hs[nl][cb] = out;
  }
  // phase B: 13 chunks, W3 chunk staged in LDS
  int rt = wv >> 1, p = wv & 1;
  f32x4 acc[10];
  #pragma unroll
  for (int j = 0; j < 10; j++) acc[j] = (f32x4){0.f, 0.f, 0.f, 0.f};
  for (int ch = 0; ch < 13; ch++) {
    __syncthreads();
    const unsigned short* src = W3c + (size_t)ch * (320 * 32);
    #pragma unroll
    for (int it = 0; it < 5; it++) {
      int idx = it * 256 + tid;
      ushort8 v = *(const ushort8*)(src + idx * 8);
      int n = idx >> 2, part = idx & 3;
      *(ushort8*)&Ws[n * 34 + part * 8] = v;
    }
    __syncthreads();
    short8 a = *(const short8*)&Hs[rt * 16 + l15][ch * 32 + quad * 8];
    #pragma unroll
    for (int j = 0; j < 10; j++) {
      int n = (p + 2 * j) * 16 + l15;
      short8 b = *(const short8*)&Ws[n * 34 + quad * 8];
      acc[j] = mfma_bf16(a, b, acc[j]);
    }
  }
  int rr = r0 + rt * 16 + quad * 4;
  #pragma unroll
  for (int j = 0; j < 10; j++) {
    int n = (p + 2 * j) * 16 + l15;
    if (n < 300) {
      #pragma unroll
      for (int r = 0; r < 4; r++) {
        int row = rr + r;
        if (row < NN) T3[(size_t)row * 304 + n] = f2b(acc[j][r]);
      }
    }
  }
}

// ---- fused layer3 agg + bias + relu + per-graph max pool (sorted batch) ----
__global__ __launch_bounds__(256, 4) void k_fused3m(
    const unsigned short* __restrict__ T3, const int* __restrict__ row_ptr,
    const Edge* __restrict__ ecs, const float* __restrict__ selfc,
    const float* __restrict__ b3, const int* __restrict__ batch,
    float* __restrict__ gbuf) {
  __shared__ unsigned int lmax[4][304];
  int tid = threadIdx.x;
  int lane = tid & 63, wv = tid >> 6;
  int r0 = blockIdx.x * 32;
  int g0 = batch[r0];
  for (int i = tid; i < 4 * 304; i += 256) ((unsigned int*)lmax)[i] = 0u;
  __syncthreads();
  bool act = lane < 38;
  int cb = lane * 8;
  for (int i = 0; i < 8; i++) {
    int node = r0 + wv * 8 + i;
    if (node >= NN) break;
    if (act) {
      float acc[8];
      #pragma unroll
      for (int j = 0; j < 8; j++) acc[j] = 0.f;
      int e0 = row_ptr[node], e1 = row_ptr[node + 1];
      int cnt = e1 - e0;
      ushort8 v0, v1, v2, v3;
      float c0, c1, c2, c3;
      GRAMP(v0, c0, 0, e0, cnt, T3, 304)
      GRAMP(v1, c1, 1, e0, cnt, T3, 304)
      GRAMP(v2, c2, 2, e0, cnt, T3, 304)
      GRAMP(v3, c3, 3, e0, cnt, T3, 304)
      for (int e = 0; e < cnt; e += 4) {
        GSTEP(v0, c0, acc, e + 0, e0, e1, cnt, T3, 304)
        GSTEP(v1, c1, acc, e + 1, e0, e1, cnt, T3, 304)
        GSTEP(v2, c2, acc, e + 2, e0, e1, cnt, T3, 304)
        GSTEP(v3, c3, acc, e + 3, e0, e1, cnt, T3, 304)
      }
      ushort8 sv = *(const ushort8*)(T3 + (size_t)node * 304 + cb);
      float sc = selfc[node];
      int slot = batch[node] - g0;
      #pragma unroll
      for (int j = 0; j < 8; j++) {
        int c = cb + j;
        if (c < 300) {
          float v = fmaxf(acc[j] + sc * u2f(sv[j]) + b3[c], 0.f);
          unsigned int uv = __float_as_uint(v);
          if (slot < 4) atomicMax(&lmax[slot][c], uv);
          else atomicMax((unsigned int*)&gbuf[(size_t)(g0 + slot) * 300 + c], uv);
        }
      }
    }
  }
  __syncthreads();
  for (int i = tid; i < 4 * 304; i += 256) {
    int s = i / 304, c = i - s * 304;
    unsigned int uv = lmax[s][c];
    int g = g0 + s;
    if (c < 300 && uv != 0u && g < NG)
      atomicMax((unsigned int*)&gbuf[(size_t)g * 300 + c], uv);
  }
}

// ---- fused head MLP: per-graph 300->200->100->6 (one block per graph) ----
__global__ __launch_bounds__(256) void k_head(
    const float* __restrict__ gbuf, const float* __restrict__ Wl1,
    const float* __restrict__ bl1, const float* __restrict__ Wl2,
    const float* __restrict__ bl2, const float* __restrict__ Wl3,
    const float* __restrict__ bl3, float* __restrict__ logits) {
  __shared__ float g[304], a1[200], a2[112];
  int gid = blockIdx.x, tid = threadIdx.x;
  for (int i = tid; i < 300; i += 256) g[i] = gbuf[(size_t)gid * 300 + i];
  __syncthreads();
  if (tid < 200) {
    float acc = bl1[tid];
    for (int k = 0; k < 300; k++) acc += g[k] * Wl1[k * 200 + tid];
    a1[tid] = fmaxf(acc, 0.f);
  }
  __syncthreads();
  if (tid < 100) {
    float acc = bl2[tid];
    for (int k = 0; k < 200; k++) acc += a1[k] * Wl2[k * 100 + tid];
    a2[tid] = fmaxf(acc, 0.f);
  }
  __syncthreads();
  if (tid < 6) {
    float acc = bl3[tid];
    for (int k = 0; k < 100; k++) acc += a2[k] * Wl3[k * 6 + tid];
    logits[gid * 6 + tid] = acc;
  }
}

__global__ void k_softmax0(const float* __restrict__ logits, float* __restrict__ out) {
  __shared__ float cmax[6], csum[6];
  int g = threadIdx.x;
  if (g < 6) {
    float m = -1e30f;
    for (int i = 0; i < NG; i++) m = fmaxf(m, logits[i * 6 + g]);
    float s = 0.f;
    for (int i = 0; i < NG; i++) s += expf(logits[i * 6 + g] - m);
    cmax[g] = m; csum[g] = s;
  }
  __syncthreads();
  for (int c = 0; c < 6; c++)
    out[g * 6 + c] = expf(logits[g * 6 + c] - cmax[c]) / csum[c];
}

extern "C" void kernel_launch(void* const* d_in, const int* in_sizes, int n_in,
                              void* d_out, int out_size, void* d_ws, size_t ws_size,
                              hipStream_t stream) {
  const float* x    = (const float*)d_in[0];
  const int*   eidx = (const int*)d_in[1];
  const int*   batch= (const int*)d_in[2];
  const float* W1 = (const float*)d_in[3];  const float* b1 = (const float*)d_in[4];
  const float* W2 = (const float*)d_in[5];  const float* b2 = (const float*)d_in[6];
  const float* W3 = (const float*)d_in[7];  const float* b3 = (const float*)d_in[8];
  const float* Wl1= (const float*)d_in[9];  const float* bl1= (const float*)d_in[10];
  const float* Wl2= (const float*)d_in[11]; const float* bl2= (const float*)d_in[12];
  const float* Wl3= (const float*)d_in[13]; const float* bl3= (const float*)d_in[14];
  const int* srcA = eidx;
  const int* dstA = eidx + NE;

  char* ws = (char*)d_ws;
  size_t off = 0;
  auto alloc = [&](size_t bytes) -> char* {
    char* p = ws + off;
    off = (off + bytes + 255) & ~(size_t)255;
    return p;
  };
  int*   counts  = (int*)  alloc((size_t)NN * 4);
  int*   row_ptr = (int*)  alloc((size_t)(NN + 1) * 4);
  int*   fill    = (int*)  alloc((size_t)NN * 4);
  int*   bsum    = (int*)  alloc(256 * 4);
  float* dinv    = (float*)alloc((size_t)NN * 4);
  float* selfc   = (float*)alloc((size_t)NN * 4);
  Edge*  ecs     = (Edge*) alloc((size_t)NE * 8);
  unsigned short* aggxb = (unsigned short*)alloc((size_t)NNP * 32 * 2);
  unsigned short* W1t   = (unsigned short*)alloc((size_t)512 * 32 * 2);
  unsigned short* W2c   = (unsigned short*)alloc((size_t)416 * 512 * 2);
  unsigned short* W3c   = (unsigned short*)alloc((size_t)320 * 416 * 2);
  float* b1p     = (float*)alloc(512 * 4);
  unsigned short* T2 = (unsigned short*)alloc((size_t)NNP * 400 * 2);
  unsigned short* T3 = (unsigned short*)alloc((size_t)NNP * 304 * 2);
  float* gbuf    = (float*)alloc((size_t)NG * 300 * 4);
  float* logits  = (float*)alloc((size_t)NG * 6 * 4);

  // CSR build (parallel scan)
  k_zero_i32<<<(NN + 255) / 256, 256, 0, stream>>>(counts, NN);
  k_count<<<(NE + 255) / 256, 256, 0, stream>>>(dstA, counts, NE);
  k_dinv<<<(NN + 255) / 256, 256, 0, stream>>>(counts, dinv, selfc, NN);
  k_scan1<<<NB_SCAN, 256, 0, stream>>>(counts, row_ptr, bsum);
  k_scan2<<<1, 256, 0, stream>>>(bsum, row_ptr);
  k_scan3<<<NB_SCAN, 256, 0, stream>>>(bsum, row_ptr, fill);
  k_fill<<<(NE + 255) / 256, 256, 0, stream>>>(srcA, dstA, row_ptr, fill, dinv, ecs, NE);
  // fused weight prep + gbuf zero
  k_prep_all<<<(PR_W1 + PR_W2 + PR_W3 + PR_B1 + PR_GB + 255) / 256, 256, 0, stream>>>(
      W1, W2, W3, b1, W1t, W2c, W3c, b1p, gbuf);
  // layers
  k_agg_x<<<(NNP + 7) / 8, 256, 0, stream>>>(x, row_ptr, ecs, selfc, aggxb, NN);
  k_fused12<<<NNP / 32, 256, 0, stream>>>(aggxb, W1t, b1p, W2c, T2);
  k_fused23<<<NNP / 32, 256, 0, stream>>>(T2, row_ptr, ecs, selfc, b2, W3c, T3);
  k_fused3m<<<NNP / 32, 256, 0, stream>>>(T3, row_ptr, ecs, selfc, b3, batch, gbuf);
  // fused head + softmax over dim 0
  k_head<<<NG, 256, 0, stream>>>(gbuf, Wl1, bl1, Wl2, bl2, Wl3, bl3, logits);
  k_softmax0<<<1, 256, 0, stream>>>(logits, (float*)d_out);
}

// Round 10
// 698.774 us; speedup vs baseline: 1.4665x; 1.0283x over previous
//
#include <hip/hip_runtime.h>
#include <hip/hip_bf16.h>

#define NN 50000
#define NNP 50016   // padded to 32*1563
#define NE 800000
#define NG 256
#define NB_SCAN 196 // ceil(NN/256)

typedef __attribute__((ext_vector_type(8))) short short8;
typedef __attribute__((ext_vector_type(8))) unsigned short ushort8;
typedef __attribute__((ext_vector_type(4))) float f32x4;

struct __align__(8) Edge { int s; float c; };

__device__ __forceinline__ float u2f(unsigned short u) {
  unsigned int t = ((unsigned int)u) << 16;
  return __builtin_bit_cast(float, t);
}
__device__ __forceinline__ unsigned short f2b(float f) {
  __hip_bfloat16 b = __float2bfloat16(f);
  return __builtin_bit_cast(unsigned short, b);
}
__device__ __forceinline__ f32x4 mfma_bf16(short8 a, short8 b, f32x4 c) {
  return __builtin_amdgcn_mfma_f32_16x16x32_bf16(a, b, c, 0, 0, 0);
}
__device__ __forceinline__ void fma8(float* acc, float c, const ushort8& v) {
  #pragma unroll
  for (int j = 0; j < 8; j++) acc[j] += c * u2f(v[j]);
}

// single-node depth-4 ring (R6 structure; R7 dual-ring was neutral)
#define GRAMP(vv, cc, S, E0, CNT, BASE, STRIDE)                         \
  if ((S) < (CNT)) { Edge ed = ecs[(E0) + (S)]; cc = ed.c;              \
    vv = *(const ushort8*)((BASE) + (size_t)ed.s * (STRIDE) + cb); }    \
  else { cc = 0.f; vv = (ushort8)0; }

#define GSTEP(vv, cc, acc, EOFF, E0, E1, CNT, BASE, STRIDE)             \
  { ushort8 tv = vv; float tc = cc; int en = (E0) + (EOFF) + 4;         \
    if (en < (E1)) { Edge ed = ecs[en]; cc = ed.c;                      \
      vv = *(const ushort8*)((BASE) + (size_t)ed.s * (STRIDE) + cb); }  \
    if ((EOFF) < (CNT)) fma8(acc, tc, tv); }

// ---------------- CSR build ----------------
__global__ void k_count(const int* __restrict__ dst, int* __restrict__ counts, int E) {
  int e = blockIdx.x * blockDim.x + threadIdx.x;
  if (e < E) atomicAdd(&counts[dst[e]], 1);
}

// ---- fat kernel: blocks <NB_SCAN do scan stage-1 + dinv/selfc + fill zero;
// blocks >=NB_SCAN do weight prep (bf16 chunk-major relayout) + gbuf zero ----
#define PR_W1 16384
#define PR_W2 212992
#define PR_W3 133120
#define PR_B1 512
#define PR_GB 76800
#define PR_TOT (PR_W1 + PR_W2 + PR_W3 + PR_B1 + PR_GB)
__global__ void k_scan1fat(const int* __restrict__ counts, int* __restrict__ row_ptr,
                           int* __restrict__ bsum, float* __restrict__ dinv,
                           float* __restrict__ selfc, int* __restrict__ fill,
                           const float* __restrict__ W1, const float* __restrict__ W2,
                           const float* __restrict__ W3, const float* __restrict__ b1,
                           unsigned short* __restrict__ W1t, unsigned short* __restrict__ W2c,
                           unsigned short* __restrict__ W3c, float* __restrict__ b1p,
                           float* __restrict__ gbuf) {
  int tid = threadIdx.x;
  if (blockIdx.x < NB_SCAN) {
    __shared__ int ws[4];
    int i = blockIdx.x * 256 + tid;
    int v = (i < NN) ? counts[i] : 0;
    if (i < NN) {
      float d = (float)v + 1.0f;
      dinv[i]  = rsqrtf(d);
      selfc[i] = 1.0f / d;
      fill[i] = 0;
    }
    int incl = v;
    #pragma unroll
    for (int off = 1; off < 64; off <<= 1) {
      int t = __shfl_up(incl, off, 64);
      if ((tid & 63) >= off) incl += t;
    }
    int wv = tid >> 6;
    if ((tid & 63) == 63) ws[wv] = incl;
    __syncthreads();
    if (tid == 0) {
      int s0 = ws[0], s1 = ws[1], s2 = ws[2], s3 = ws[3];
      ws[0] = 0; ws[1] = s0; ws[2] = s0 + s1; ws[3] = s0 + s1 + s2;
      bsum[blockIdx.x] = s0 + s1 + s2 + s3;
    }
    __syncthreads();
    if (i < NN) row_ptr[i] = ws[wv] + incl - v;
    return;
  }
  int idx = (blockIdx.x - NB_SCAN) * 256 + tid;
  if (idx < PR_W1) {
    int n = idx >> 5, k = idx & 31;
    W1t[idx] = f2b((n < 500 && k < 19) ? W1[k * 500 + n] : 0.f);
    return;
  }
  idx -= PR_W1;
  if (idx < PR_W2) {
    int n = idx >> 9, k = idx & 511;
    float v = (n < 400 && k < 500) ? W2[k * 400 + n] : 0.f;
    int ch = k >> 5, kk = k & 31;
    W2c[((size_t)ch * 416 + n) * 32 + kk] = f2b(v);
    return;
  }
  idx -= PR_W2;
  if (idx < PR_W3) {
    int n = idx / 416, k = idx - n * 416;
    float v = (n < 300 && k < 400) ? W3[k * 300 + n] : 0.f;
    int ch = k >> 5, kk = k & 31;
    W3c[((size_t)ch * 320 + n) * 32 + kk] = f2b(v);
    return;
  }
  idx -= PR_W3;
  if (idx < PR_B1) { b1p[idx] = (idx < 500) ? b1[idx] : 0.f; return; }
  idx -= PR_B1;
  if (idx < PR_GB) gbuf[idx] = 0.f;
}

__global__ void k_scan2(int* __restrict__ bsum, int* __restrict__ row_ptr) {
  __shared__ int ws[4];
  int tid = threadIdx.x;
  int v = (tid < NB_SCAN) ? bsum[tid] : 0;
  int incl = v;
  #pragma unroll
  for (int off = 1; off < 64; off <<= 1) {
    int t = __shfl_up(incl, off, 64);
    if ((tid & 63) >= off) incl += t;
  }
  int wv = tid >> 6;
  if ((tid & 63) == 63) ws[wv] = incl;
  __syncthreads();
  if (tid == 0) {
    int s0 = ws[0], s1 = ws[1], s2 = ws[2], s3 = ws[3];
    ws[0] = 0; ws[1] = s0; ws[2] = s0 + s1; ws[3] = s0 + s1 + s2;
    row_ptr[NN] = s0 + s1 + s2 + s3;
  }
  __syncthreads();
  if (tid < NB_SCAN) bsum[tid] = ws[wv] + incl - v;
}
__global__ void k_scan3(const int* __restrict__ bsum, int* __restrict__ row_ptr) {
  int i = blockIdx.x * 256 + threadIdx.x;
  if (i < NN) row_ptr[i] += bsum[blockIdx.x];
}

__global__ void k_fill(const int* __restrict__ src, const int* __restrict__ dst,
                       const int* __restrict__ row_ptr, int* __restrict__ fill,
                       const float* __restrict__ dinv, Edge* __restrict__ ecs, int E) {
  int e = blockIdx.x * blockDim.x + threadIdx.x;
  if (e < E) {
    int s = src[e], d = dst[e];
    int pos = row_ptr[d] + atomicAdd(&fill[d], 1);
    Edge ed; ed.s = s; ed.c = dinv[s] * dinv[d];
    ecs[pos] = ed;
  }
}

// ---------------- layer-1 aggregation of x -> bf16 [NNP][32] ----------------
__global__ __launch_bounds__(256, 4) void k_agg_x(
    const float* __restrict__ x, const int* __restrict__ row_ptr,
    const Edge* __restrict__ ecs, const float* __restrict__ selfc,
    unsigned short* __restrict__ aggxb, int n) {
  int tid  = threadIdx.x;
  int node = blockIdx.x * 8 + (tid >> 5);
  int lane = tid & 31;
  if (node >= NNP) return;
  float acc = 0.f;
  if (node < n && lane < 19) {
    int e0 = row_ptr[node], e1 = row_ptr[node + 1];
    int cnt = e1 - e0;
    float v0 = 0.f, v1 = 0.f, v2 = 0.f, v3 = 0.f;
    float c0 = 0.f, c1 = 0.f, c2 = 0.f, c3 = 0.f;
    if (cnt > 0) { Edge ed = ecs[e0];     c0 = ed.c; v0 = x[(size_t)ed.s * 19 + lane]; }
    if (cnt > 1) { Edge ed = ecs[e0 + 1]; c1 = ed.c; v1 = x[(size_t)ed.s * 19 + lane]; }
    if (cnt > 2) { Edge ed = ecs[e0 + 2]; c2 = ed.c; v2 = x[(size_t)ed.s * 19 + lane]; }
    if (cnt > 3) { Edge ed = ecs[e0 + 3]; c3 = ed.c; v3 = x[(size_t)ed.s * 19 + lane]; }
    for (int e = 0; e < cnt; e += 4) {
      float tv, tc; int en;
      tv = v0; tc = c0; en = e0 + e + 4;
      if (en < e1) { Edge ed = ecs[en]; c0 = ed.c; v0 = x[(size_t)ed.s * 19 + lane]; }
      if (e < cnt) acc += tc * tv;
      tv = v1; tc = c1; en = e0 + e + 5;
      if (en < e1) { Edge ed = ecs[en]; c1 = ed.c; v1 = x[(size_t)ed.s * 19 + lane]; }
      if (e + 1 < cnt) acc += tc * tv;
      tv = v2; tc = c2; en = e0 + e + 6;
      if (en < e1) { Edge ed = ecs[en]; c2 = ed.c; v2 = x[(size_t)ed.s * 19 + lane]; }
      if (e + 2 < cnt) acc += tc * tv;
      tv = v3; tc = c3; en = e0 + e + 7;
      if (en < e1) { Edge ed = ecs[en]; c3 = ed.c; v3 = x[(size_t)ed.s * 19 + lane]; }
      if (e + 3 < cnt) acc += tc * tv;
    }
    acc += selfc[node] * x[(size_t)node * 19 + lane];
  }
  aggxb[(size_t)node * 32 + lane] = (node < n && lane < 19) ? f2b(acc) : (unsigned short)0;
}

// ---- fused layer1+2: T2 = (relu(aggx@W1+b1)) @ W2, MFMA ----
// Ws stride 40 shorts: staging-write banks (20n+4p)%32 = 2-way (free, m136);
// R9's 34-stride writes were (17n+4p)%32 -> 1.0e7 conflicts.
__global__ __launch_bounds__(256) void k_fused12(
    const unsigned short* __restrict__ aggxb, const unsigned short* __restrict__ W1t,
    const float* __restrict__ b1p, const unsigned short* __restrict__ W2c,
    unsigned short* __restrict__ T2) {
  __shared__ unsigned short Hs[32][520];   // 33280 B
  __shared__ unsigned short Ws[416 * 40];  // 33280 B
  int tid = threadIdx.x;
  int lane = tid & 63, wv = tid >> 6;
  int l15 = lane & 15, quad = lane >> 4;
  int r0 = blockIdx.x * 32;
  // phase A: Hs = relu(aggx@W1 + b1)
  for (int t = wv; t < 64; t += 4) {
    int rt = t & 1, ct = t >> 1;
    short8 a = *(const short8*)(aggxb + (size_t)(r0 + rt * 16 + l15) * 32 + quad * 8);
    short8 b = *(const short8*)(W1t + (size_t)(ct * 16 + l15) * 32 + quad * 8);
    f32x4 c = {0.f, 0.f, 0.f, 0.f};
    c = mfma_bf16(a, b, c);
    int col = ct * 16 + l15;
    float bias = b1p[col];
    int rbase = rt * 16 + quad * 4;
    #pragma unroll
    for (int r = 0; r < 4; r++)
      Hs[rbase + r][col] = f2b(fmaxf(c[r] + bias, 0.f));
  }
  // phase B: 16 chunks of K=32, W2 chunk staged in LDS per iteration
  int rt = wv >> 1, p = wv & 1;
  f32x4 acc[13];
  #pragma unroll
  for (int j = 0; j < 13; j++) acc[j] = (f32x4){0.f, 0.f, 0.f, 0.f};
  for (int ch = 0; ch < 16; ch++) {
    __syncthreads();
    const unsigned short* src = W2c + (size_t)ch * (416 * 32);
    #pragma unroll
    for (int it = 0; it < 7; it++) {
      int idx = it * 256 + tid;
      if (idx < 1664) {
        ushort8 v = *(const ushort8*)(src + idx * 8);
        int n = idx >> 2, part = idx & 3;
        *(ushort8*)&Ws[n * 40 + part * 8] = v;
      }
    }
    __syncthreads();
    short8 a = *(const short8*)&Hs[rt * 16 + l15][ch * 32 + quad * 8];
    #pragma unroll
    for (int j = 0; j < 13; j++) {
      int n = (p + 2 * j) * 16 + l15;
      short8 b = *(const short8*)&Ws[n * 40 + quad * 8];
      acc[j] = mfma_bf16(a, b, acc[j]);
    }
  }
  int rr = r0 + rt * 16 + quad * 4;
  #pragma unroll
  for (int j = 0; j < 13; j++) {
    int n = (p + 2 * j) * 16 + l15;
    if (n < 400) {
      #pragma unroll
      for (int r = 0; r < 4; r++) {
        int row = rr + r;
        if (row < NN) T2[(size_t)row * 400 + n] = f2b(acc[j][r]);
      }
    }
  }
}

// ---- fused layer2 agg + layer3 linear: T3 = relu(agg(T2)+b2) @ W3 (MFMA) ----
__global__ __launch_bounds__(256, 4) void k_fused23(
    const unsigned short* __restrict__ T2, const int* __restrict__ row_ptr,
    const Edge* __restrict__ ecs, const float* __restrict__ selfc,
    const float* __restrict__ b2, const unsigned short* __restrict__ W3c,
    unsigned short* __restrict__ T3) {
  __shared__ unsigned short Hs[32][424];   // 27136 B
  __shared__ unsigned short Ws[320 * 40];  // 25600 B
  int tid = threadIdx.x;
  int lane = tid & 63, wv = tid >> 6;
  int l15 = lane & 15, quad = lane >> 4;
  int r0 = blockIdx.x * 32;
  bool act = lane < 50;
  int cb = lane * 8;
  for (int i = 0; i < 8; i++) {
    int nl = wv + 4 * i;
    int node = r0 + nl;
    ushort8 out = (ushort8)0;
    if (node < NN && act) {
      float acc[8];
      #pragma unroll
      for (int j = 0; j < 8; j++) acc[j] = 0.f;
      int e0 = row_ptr[node], e1 = row_ptr[node + 1];
      int cnt = e1 - e0;
      ushort8 v0, v1, v2, v3;
      float c0, c1, c2, c3;
      GRAMP(v0, c0, 0, e0, cnt, T2, 400)
      GRAMP(v1, c1, 1, e0, cnt, T2, 400)
      GRAMP(v2, c2, 2, e0, cnt, T2, 400)
      GRAMP(v3, c3, 3, e0, cnt, T2, 400)
      for (int e = 0; e < cnt; e += 4) {
        GSTEP(v0, c0, acc, e + 0, e0, e1, cnt, T2, 400)
        GSTEP(v1, c1, acc, e + 1, e0, e1, cnt, T2, 400)
        GSTEP(v2, c2, acc, e + 2, e0, e1, cnt, T2, 400)
        GSTEP(v3, c3, acc, e + 3, e0, e1, cnt, T2, 400)
      }
      ushort8 sv = *(const ushort8*)(T2 + (size_t)node * 400 + cb);
      float sc = selfc[node];
      #pragma unroll
      for (int j = 0; j < 8; j++)
        out[j] = f2b(fmaxf(acc[j] + sc * u2f(sv[j]) + b2[cb + j], 0.f));
    }
    if (lane < 52) *(ushort8*)&Hs[nl][cb] = out;
  }
  // phase B: 13 chunks, W3 chunk staged in LDS
  int rt = wv >> 1, p = wv & 1;
  f32x4 acc[10];
  #pragma unroll
  for (int j = 0; j < 10; j++) acc[j] = (f32x4){0.f, 0.f, 0.f, 0.f};
  for (int ch = 0; ch < 13; ch++) {
    __syncthreads();
    const unsigned short* src = W3c + (size_t)ch * (320 * 32);
    #pragma unroll
    for (int it = 0; it < 5; it++) {
      int idx = it * 256 + tid;
      ushort8 v = *(const ushort8*)(src + idx * 8);
      int n = idx >> 2, part = idx & 3;
      *(ushort8*)&Ws[n * 40 + part * 8] = v;
    }
    __syncthreads();
    short8 a = *(const short8*)&Hs[rt * 16 + l15][ch * 32 + quad * 8];
    #pragma unroll
    for (int j = 0; j < 10; j++) {
      int n = (p + 2 * j) * 16 + l15;
      short8 b = *(const short8*)&Ws[n * 40 + quad * 8];
      acc[j] = mfma_bf16(a, b, acc[j]);
    }
  }
  int rr = r0 + rt * 16 + quad * 4;
  #pragma unroll
  for (int j = 0; j < 10; j++) {
    int n = (p + 2 * j) * 16 + l15;
    if (n < 300) {
      #pragma unroll
      for (int r = 0; r < 4; r++) {
        int row = rr + r;
        if (row < NN) T3[(size_t)row * 304 + n] = f2b(acc[j][r]);
      }
    }
  }
}

// ---- fused layer3 agg + bias + relu + per-graph max pool (sorted batch) ----
__global__ __launch_bounds__(256, 4) void k_fused3m(
    const unsigned short* __restrict__ T3, const int* __restrict__ row_ptr,
    const Edge* __restrict__ ecs, const float* __restrict__ selfc,
    const float* __restrict__ b3, const int* __restrict__ batch,
    float* __restrict__ gbuf) {
  __shared__ unsigned int lmax[4][304];
  int tid = threadIdx.x;
  int lane = tid & 63, wv = tid >> 6;
  int r0 = blockIdx.x * 32;
  int g0 = batch[r0];
  for (int i = tid; i < 4 * 304; i += 256) ((unsigned int*)lmax)[i] = 0u;
  __syncthreads();
  bool act = lane < 38;
  int cb = lane * 8;
  for (int i = 0; i < 8; i++) {
    int node = r0 + wv * 8 + i;
    if (node >= NN) break;
    if (act) {
      float acc[8];
      #pragma unroll
      for (int j = 0; j < 8; j++) acc[j] = 0.f;
      int e0 = row_ptr[node], e1 = row_ptr[node + 1];
      int cnt = e1 - e0;
      ushort8 v0, v1, v2, v3;
      float c0, c1, c2, c3;
      GRAMP(v0, c0, 0, e0, cnt, T3, 304)
      GRAMP(v1, c1, 1, e0, cnt, T3, 304)
      GRAMP(v2, c2, 2, e0, cnt, T3, 304)
      GRAMP(v3, c3, 3, e0, cnt, T3, 304)
      for (int e = 0; e < cnt; e += 4) {
        GSTEP(v0, c0, acc, e + 0, e0, e1, cnt, T3, 304)
        GSTEP(v1, c1, acc, e + 1, e0, e1, cnt, T3, 304)
        GSTEP(v2, c2, acc, e + 2, e0, e1, cnt, T3, 304)
        GSTEP(v3, c3, acc, e + 3, e0, e1, cnt, T3, 304)
      }
      ushort8 sv = *(const ushort8*)(T3 + (size_t)node * 304 + cb);
      float sc = selfc[node];
      int slot = batch[node] - g0;
      #pragma unroll
      for (int j = 0; j < 8; j++) {
        int c = cb + j;
        if (c < 300) {
          float v = fmaxf(acc[j] + sc * u2f(sv[j]) + b3[c], 0.f);
          unsigned int uv = __float_as_uint(v);
          if (slot < 4) atomicMax(&lmax[slot][c], uv);
          else atomicMax((unsigned int*)&gbuf[(size_t)(g0 + slot) * 300 + c], uv);
        }
      }
    }
  }
  __syncthreads();
  for (int i = tid; i < 4 * 304; i += 256) {
    int s = i / 304, c = i - s * 304;
    unsigned int uv = lmax[s][c];
    int g = g0 + s;
    if (c < 300 && uv != 0u && g < NG)
      atomicMax((unsigned int*)&gbuf[(size_t)g * 300 + c], uv);
  }
}

// ---- fused head MLP: per-graph 300->200->100->6 (one block per graph) ----
__global__ __launch_bounds__(256) void k_head(
    const float* __restrict__ gbuf, const float* __restrict__ Wl1,
    const float* __restrict__ bl1, const float* __restrict__ Wl2,
    const float* __restrict__ bl2, const float* __restrict__ Wl3,
    const float* __restrict__ bl3, float* __restrict__ logits) {
  __shared__ float g[304], a1[200], a2[112];
  int gid = blockIdx.x, tid = threadIdx.x;
  for (int i = tid; i < 300; i += 256) g[i] = gbuf[(size_t)gid * 300 + i];
  __syncthreads();
  if (tid < 200) {
    float acc = bl1[tid];
    for (int k = 0; k < 300; k++) acc += g[k] * Wl1[k * 200 + tid];
    a1[tid] = fmaxf(acc, 0.f);
  }
  __syncthreads();
  if (tid < 100) {
    float acc = bl2[tid];
    for (int k = 0; k < 200; k++) acc += a1[k] * Wl2[k * 100 + tid];
    a2[tid] = fmaxf(acc, 0.f);
  }
  __syncthreads();
  if (tid < 6) {
    float acc = bl3[tid];
    for (int k = 0; k < 100; k++) acc += a2[k] * Wl3[k * 6 + tid];
    logits[gid * 6 + tid] = acc;
  }
}

__global__ void k_softmax0(const float* __restrict__ logits, float* __restrict__ out) {
  __shared__ float cmax[6], csum[6];
  int g = threadIdx.x;
  if (g < 6) {
    float m = -1e30f;
    for (int i = 0; i < NG; i++) m = fmaxf(m, logits[i * 6 + g]);
    float s = 0.f;
    for (int i = 0; i < NG; i++) s += expf(logits[i * 6 + g] - m);
    cmax[g] = m; csum[g] = s;
  }
  __syncthreads();
  for (int c = 0; c < 6; c++)
    out[g * 6 + c] = expf(logits[g * 6 + c] - cmax[c]) / csum[c];
}

extern "C" void kernel_launch(void* const* d_in, const int* in_sizes, int n_in,
                              void* d_out, int out_size, void* d_ws, size_t ws_size,
                              hipStream_t stream) {
  const float* x    = (const float*)d_in[0];
  const int*   eidx = (const int*)d_in[1];
  const int*   batch= (const int*)d_in[2];
  const float* W1 = (const float*)d_in[3];  const float* b1 = (const float*)d_in[4];
  const float* W2 = (const float*)d_in[5];  const float* b2 = (const float*)d_in[6];
  const float* W3 = (const float*)d_in[7];  const float* b3 = (const float*)d_in[8];
  const float* Wl1= (const float*)d_in[9];  const float* bl1= (const float*)d_in[10];
  const float* Wl2= (const float*)d_in[11]; const float* bl2= (const float*)d_in[12];
  const float* Wl3= (const float*)d_in[13]; const float* bl3= (const float*)d_in[14];
  const int* srcA = eidx;
  const int* dstA = eidx + NE;

  char* ws = (char*)d_ws;
  size_t off = 0;
  auto alloc = [&](size_t bytes) -> char* {
    char* p = ws + off;
    off = (off + bytes + 255) & ~(size_t)255;
    return p;
  };
  int*   counts  = (int*)  alloc((size_t)NN * 4);
  int*   row_ptr = (int*)  alloc((size_t)(NN + 1) * 4);
  int*   fill    = (int*)  alloc((size_t)NN * 4);
  int*   bsum    = (int*)  alloc(256 * 4);
  float* dinv    = (float*)alloc((size_t)NN * 4);
  float* selfc   = (float*)alloc((size_t)NN * 4);
  Edge*  ecs     = (Edge*) alloc((size_t)NE * 8);
  unsigned short* aggxb = (unsigned short*)alloc((size_t)NNP * 32 * 2);
  unsigned short* W1t   = (unsigned short*)alloc((size_t)512 * 32 * 2);
  unsigned short* W2c   = (unsigned short*)alloc((size_t)416 * 512 * 2);
  unsigned short* W3c   = (unsigned short*)alloc((size_t)320 * 416 * 2);
  float* b1p     = (float*)alloc(512 * 4);
  unsigned short* T2 = (unsigned short*)alloc((size_t)NNP * 400 * 2);
  unsigned short* T3 = (unsigned short*)alloc((size_t)NNP * 304 * 2);
  float* gbuf    = (float*)alloc((size_t)NG * 300 * 4);
  float* logits  = (float*)alloc((size_t)NG * 6 * 4);

  // CSR build (memset + parallel scan; dinv/prep fused into scan1 fat kernel)
  hipMemsetAsync(counts, 0, (size_t)NN * 4, stream);
  k_count<<<(NE + 255) / 256, 256, 0, stream>>>(dstA, counts, NE);
  k_scan1fat<<<NB_SCAN + (PR_TOT + 255) / 256, 256, 0, stream>>>(
      counts, row_ptr, bsum, dinv, selfc, fill,
      W1, W2, W3, b1, W1t, W2c, W3c, b1p, gbuf);
  k_scan2<<<1, 256, 0, stream>>>(bsum, row_ptr);
  k_scan3<<<NB_SCAN, 256, 0, stream>>>(bsum, row_ptr);
  k_fill<<<(NE + 255) / 256, 256, 0, stream>>>(srcA, dstA, row_ptr, fill, dinv, ecs, NE);
  // layers
  k_agg_x<<<(NNP + 7) / 8, 256, 0, stream>>>(x, row_ptr, ecs, selfc, aggxb, NN);
  k_fused12<<<NNP / 32, 256, 0, stream>>>(aggxb, W1t, b1p, W2c, T2);
  k_fused23<<<NNP / 32, 256, 0, stream>>>(T2, row_ptr, ecs, selfc, b2, W3c, T3);
  k_fused3m<<<NNP / 32, 256, 0, stream>>>(T3, row_ptr, ecs, selfc, b3, batch, gbuf);
  // head + softmax over dim 0
  k_head<<<NG, 256, 0, stream>>>(gbuf, Wl1, bl1, Wl2, bl2, Wl3, bl3, logits);
  k_softmax0<<<1, 256, 0, stream>>>(logits, (float*)d_out);
}